// Round 1
// 1414.970 us; speedup vs baseline: 1.2445x; 1.2445x over previous
//
#include <hip/hip_runtime.h>
#include <math.h>

typedef _Float16 f16;
typedef f16 f16x8 __attribute__((ext_vector_type(8)));
typedef f16 f16x2 __attribute__((ext_vector_type(2)));
typedef float f32x4 __attribute__((ext_vector_type(4)));

// ---------------- weight prep: fp32 -> fp16, conv weights to [n][k] with
// k-order matching the conv A-staging chunk layout ----------------
__global__ __launch_bounds__(256) void k_prep(const float* __restrict__ c1w,
                                              const float* __restrict__ c2w,
                                              const float* __restrict__ c3w,
                                              const float* __restrict__ fcw,
                                              const float* __restrict__ wih,
                                              const float* __restrict__ qkvw,
                                              const float* __restrict__ projw,
                                              f16* __restrict__ W1, f16* __restrict__ W2,
                                              f16* __restrict__ W3, f16* __restrict__ FCW,
                                              f16* __restrict__ WIH, f16* __restrict__ QKVW,
                                              f16* __restrict__ PROJW) {
    int i0 = blockIdx.x * 256 + threadIdx.x;
    if (i0 < 8192) {                       // conv1: k = kh*32 + c*8 + kw
        int n = i0 >> 8, k = i0 & 255;
        int kh = k >> 5, r = k & 31, c = r >> 3, kw = r & 7;
        W1[i0] = (f16)c1w[((n * 4 + c) * 8 + kh) * 8 + kw];
    } else if (i0 < 8192 + 32768) {        // conv2: k = kh*128 + kw*32 + c
        int i = i0 - 8192;
        int n = i >> 9, k = i & 511;
        int kh = k >> 7, r = k & 127, kw = r >> 5, c = r & 31;
        W2[i] = (f16)c2w[((n * 32 + c) * 4 + kh) * 4 + kw];
    } else if (i0 < 8192 + 32768 + 36864) {  // conv3: k = kh*192 + kw*64 + c
        int i = i0 - (8192 + 32768);
        int n = i / 576, k = i % 576;
        int kh = k / 192, r = k % 192, kw = r / 64, c = r & 63;
        W3[i] = (f16)c3w[((n * 64 + c) * 3 + kh) * 3 + kw];
    } else if (i0 < 8192 + 32768 + 36864 + 589824) {  // FC: k = p*64 + c (NHWC flat)
        int i = i0 - (8192 + 32768 + 36864);
        int o = i / 2304, k = i % 2304, p = k >> 6, c = k & 63;
        FCW[i] = (f16)fcw[o * 2304 + c * 36 + p];
    } else if (i0 < 765952) {
        int i = i0 - (8192 + 32768 + 36864 + 589824);
        WIH[i] = (f16)wih[i];
    } else if (i0 < 765952 + 12288) {      // qkv weight, q rows pre-scaled by 0.25
        int i = i0 - 765952;
        QKVW[i] = (f16)(qkvw[i] * ((i < 4096) ? 0.25f : 1.f));
    } else if (i0 < 765952 + 12288 + 4096) {
        int i = i0 - (765952 + 12288);
        PROJW[i] = (f16)projw[i];
    }
}

// ---------------- implicit-GEMM MFMA conv (NHWC fp16 in/out, ReLU) --------
// Block = 64 output pixels (4 waves x 16-pixel m-tiles) x all NCH channels.
// K-loop chunks over kh; within-chunk k = contiguous (kw,c) run in NHWC.
template <int CINP, int KH, int KW, int STRIDE, int IW, int OW, int PPI, int NCH, bool SRCF32>
__global__ __launch_bounds__(256) void k_conv(const void* __restrict__ srcv,
                                              const f16* __restrict__ W,  // [NCH][KH*CK]
                                              const float* __restrict__ bias,
                                              f16* __restrict__ dst) {
    constexpr int CK = KW * CINP;      // within-chunk K (32 / 128 / 192)
    constexpr int KS = CK / 32;        // MFMA k-steps per chunk
    constexpr int NT = NCH / 16;       // n-tiles
    constexpr int LA = CK + 8;         // padded LDS row (halves): 16B-aligned, conflict-free
    constexpr int AUN = SRCF32 ? 64 * CINP : (64 * CK) / 8;
    constexpr int WUN = (NCH * CK) / 8;
    constexpr int ANU = (AUN + 255) / 256;
    constexpr int WNU = (WUN + 255) / 256;
    __shared__ f16 As[64 * LA];
    __shared__ f16 Bs[NCH * LA];
    const int tid = threadIdx.x;
    const int wave = tid >> 6, lane = tid & 63;
    const int m0 = blockIdx.x * 64;

    int aGB[ANU], aLO[ANU];
#pragma unroll
    for (int j = 0; j < ANU; j++) {
        int u = tid + j * 256;
        if (u < AUN) {
            if (SRCF32) {  // conv1: src NCHW fp32; unit = (pixel, channel-plane), 8-float run
                int px = u / CINP, c = u % CINP;
                int m = m0 + px, n = m / PPI, pp = m % PPI, oy = pp / OW, ox = pp % OW;
                aGB[j] = ((n * CINP + c) * IW + oy * STRIDE) * IW + ox * STRIDE;
                aLO[j] = px * LA + c * 8;
            } else {       // NHWC fp16: unit = 16B segment of the contiguous KW*CINP run
                constexpr int SPP = CK / 8;
                int px = u / SPP, seg = u % SPP;
                int m = m0 + px, n = m / PPI, pp = m % PPI, oy = pp / OW, ox = pp % OW;
                aGB[j] = ((n * IW + oy * STRIDE) * IW + ox * STRIDE) * CINP + seg * 8;
                aLO[j] = px * LA + seg * 8;
            }
        }
    }
    int wGB[WNU], wLO[WNU];
#pragma unroll
    for (int j = 0; j < WNU; j++) {
        int u = tid + j * 256;
        if (u < WUN) {
            constexpr int SPP = CK / 8;
            int n = u / SPP, seg = u % SPP;
            wGB[j] = n * (KH * CK) + seg * 8;
            wLO[j] = n * LA + seg * 8;
        }
    }

    f32x4 acc[NT] = {};
    const f16* ap = As + (wave * 16 + (lane & 15)) * LA + (lane >> 4) * 8;
    const f16* bp = Bs + (lane & 15) * LA + (lane >> 4) * 8;

    for (int kh = 0; kh < KH; kh++) {
        __syncthreads();
#pragma unroll
        for (int j = 0; j < ANU; j++) {
            int u = tid + j * 256;
            if (u < AUN) {
                if (SRCF32) {
                    const float* s = (const float*)srcv + aGB[j] + kh * IW;
                    float4 v0 = *(const float4*)s;
                    float4 v1 = *(const float4*)(s + 4);
                    f16x8 h;
                    h[0] = (f16)v0.x; h[1] = (f16)v0.y; h[2] = (f16)v0.z; h[3] = (f16)v0.w;
                    h[4] = (f16)v1.x; h[5] = (f16)v1.y; h[6] = (f16)v1.z; h[7] = (f16)v1.w;
                    *(f16x8*)(As + aLO[j]) = h;
                } else {
                    const f16* s = (const f16*)srcv + aGB[j] + kh * (IW * CINP);
                    *(f16x8*)(As + aLO[j]) = *(const f16x8*)s;
                }
            }
        }
#pragma unroll
        for (int j = 0; j < WNU; j++) {
            int u = tid + j * 256;
            if (u < WUN)
                *(f16x8*)(Bs + wLO[j]) = *(const f16x8*)(W + wGB[j] + kh * CK);
        }
        __syncthreads();
#pragma unroll
        for (int ks = 0; ks < KS; ks++) {
            f16x8 af = *(const f16x8*)(ap + ks * 32);
#pragma unroll
            for (int nt = 0; nt < NT; nt++) {
                f16x8 bf = *(const f16x8*)(bp + nt * 16 * LA + ks * 32);
                acc[nt] = __builtin_amdgcn_mfma_f32_16x16x32_f16(af, bf, acc[nt], 0, 0, 0);
            }
        }
    }
    __syncthreads();
    {   // bias+ReLU, restage through LDS for coalesced fp16 NHWC store
        int rrow = wave * 16 + ((lane >> 4) << 2);
        int col = lane & 15;
#pragma unroll
        for (int nt = 0; nt < NT; nt++) {
            float bb = bias[nt * 16 + col];
#pragma unroll
            for (int r = 0; r < 4; r++) {
                float v = acc[nt][r] + bb;
                As[(rrow + r) * NCH + nt * 16 + col] = (f16)fmaxf(v, 0.f);
            }
        }
    }
    __syncthreads();
    constexpr int OUN = 64 * NCH / 8;
    for (int u = tid; u < OUN; u += 256) {
        int px = u / (NCH / 8), seg = u % (NCH / 8);
        *(f16x8*)(dst + (size_t)(m0 + px) * NCH + seg * 8) = *(const f16x8*)(As + px * NCH + seg * 8);
    }
}

// ---------------- MFMA GEMM: C = act(A(MxK,f16) @ W(NxK,f16)^T + bias [+ R]) ----
template <bool RELU, bool OUTF32, bool RESID>
__global__ __launch_bounds__(256) void k_gemm16(const f16* __restrict__ A,
                                                const f16* __restrict__ W,
                                                const float* __restrict__ bias,
                                                const f16* __restrict__ R,
                                                void* __restrict__ Cv, int N, int K) {
    __shared__ f16 As[64 * 72];
    __shared__ f16 Bs[64 * 72];
    int tid = threadIdx.x, wave = tid >> 6, lane = tid & 63;
    int n0 = blockIdx.x * 64, m0 = blockIdx.y * 64;
    f32x4 acc[4] = {};
    const f16* ap = As + (wave * 16 + (lane & 15)) * 72 + (lane >> 4) * 8;
    const f16* bp = Bs + (lane & 15) * 72 + (lane >> 4) * 8;
    int arow = tid >> 3, aseg = tid & 7;
    for (int k0 = 0; k0 < K; k0 += 64) {
        __syncthreads();
        *(f16x8*)(As + arow * 72 + aseg * 8) = *(const f16x8*)(A + (size_t)(m0 + arow) * K + k0 + aseg * 8);
        *(f16x8*)(As + (arow + 32) * 72 + aseg * 8) = *(const f16x8*)(A + (size_t)(m0 + arow + 32) * K + k0 + aseg * 8);
        *(f16x8*)(Bs + arow * 72 + aseg * 8) = *(const f16x8*)(W + (size_t)(n0 + arow) * K + k0 + aseg * 8);
        *(f16x8*)(Bs + (arow + 32) * 72 + aseg * 8) = *(const f16x8*)(W + (size_t)(n0 + arow + 32) * K + k0 + aseg * 8);
        __syncthreads();
#pragma unroll
        for (int ks = 0; ks < 2; ks++) {
            f16x8 af = *(const f16x8*)(ap + ks * 32);
#pragma unroll
            for (int nt = 0; nt < 4; nt++) {
                f16x8 bf = *(const f16x8*)(bp + nt * 16 * 72 + ks * 32);
                acc[nt] = __builtin_amdgcn_mfma_f32_16x16x32_f16(af, bf, acc[nt], 0, 0, 0);
            }
        }
    }
    int mrow = m0 + wave * 16 + ((lane >> 4) << 2);
    int col = n0 + (lane & 15);
#pragma unroll
    for (int nt = 0; nt < 4; nt++) {
        float bb = bias[col + nt * 16];
#pragma unroll
        for (int r = 0; r < 4; r++) {
            float v = acc[nt][r] + bb;
            if (RESID) v += (float)R[(size_t)(mrow + r) * N + col + nt * 16];
            if (RELU) v = fmaxf(v, 0.f);
            if (OUTF32) ((float*)Cv)[(size_t)(mrow + r) * N + col + nt * 16] = v;
            else ((f16*)Cv)[(size_t)(mrow + r) * N + col + nt * 16] = (f16)v;
        }
    }
}

// ---------------- CBAM channel+spatial gates, in-place on NHWC fp16 h3 ----
// 4 samples per block, one wave (64 lanes) per sample.
__global__ __launch_bounds__(256) void k_gate(f16* __restrict__ h3,
                                              const float* __restrict__ fc1w,
                                              const float* __restrict__ fc2w,
                                              const float* __restrict__ spw) {
    __shared__ float tok[4][36][67];   // pad 67: coprime with 32 banks for row-walks
    __shared__ float pm[4][64], px[4][64], hml[4][32], chv[4][64];
    __shared__ float spm[4][36], spx[4][36], gsp[4][36];
    int s = threadIdx.x >> 6, lane = threadIdx.x & 63;
    f16* hb = h3 + (size_t)(blockIdx.x * 4 + s) * 2304;
    for (int i = lane; i < 2304; i += 64) tok[s][i >> 6][i & 63] = (float)hb[i];
    __syncthreads();
    {   // channel stats: lane = channel
        float m = 0.f, mx = -1e30f;
        for (int p = 0; p < 36; p++) { float v = tok[s][p][lane]; m += v; mx = fmaxf(mx, v); }
        pm[s][lane] = m * (1.f / 36.f); px[s][lane] = mx;
    }
    __syncthreads();
    if (lane < 32) {
        int j = lane & 15;
        const float* srcv = (lane < 16) ? pm[s] : px[s];
        float acc = 0.f;
        for (int c = 0; c < 64; c++) acc += fc1w[j * 64 + c] * srcv[c];
        hml[s][lane] = fmaxf(acc, 0.f);
    }
    __syncthreads();
    {
        float acc = 0.f;
        for (int j = 0; j < 16; j++) acc += fc2w[lane * 16 + j] * (hml[s][j] + hml[s][16 + j]);
        chv[s][lane] = 1.f / (1.f + expf(-acc));
    }
    __syncthreads();
    if (lane < 36) {   // channel gate + spatial stats, lane = token
        float m = 0.f, mx = -1e30f;
        for (int c = 0; c < 64; c++) {
            float v = tok[s][lane][c] * chv[s][c];
            tok[s][lane][c] = v; m += v; mx = fmaxf(mx, v);
        }
        spm[s][lane] = m * (1.f / 64.f); spx[s][lane] = mx;
    }
    __syncthreads();
    if (lane < 36) {   // 7x7 spatial conv on 6x6 mean/max maps
        int y = lane / 6, x = lane % 6;
        float acc = 0.f;
        for (int dy = 0; dy < 7; dy++) {
            int yy = y + dy - 3; if (yy < 0 || yy > 5) continue;
            for (int dx = 0; dx < 7; dx++) {
                int xx = x + dx - 3; if (xx < 0 || xx > 5) continue;
                int pp = yy * 6 + xx;
                acc += spw[dy * 7 + dx] * spm[s][pp] + spw[49 + dy * 7 + dx] * spx[s][pp];
            }
        }
        gsp[s][lane] = 1.f / (1.f + expf(-acc));
    }
    __syncthreads();
    for (int i = lane; i < 2304; i += 64) {
        int p = i >> 6;
        hb[i] = (f16)(tok[s][p][i & 63] * gsp[s][p]);
    }
}

// ---------------- per-sample attention core: scores -> softmax -> PV ------
// qkv rows: [q0..63 (pre-scaled) | k0..63 | v0..63] per token.
__global__ __launch_bounds__(256) void k_attn(const f16* __restrict__ qkv,
                                              f16* __restrict__ attout) {
    __shared__ f16 t[36][200];     // q[0..63] k[64..127] v[128..191], pad to 200
    __shared__ f16 att[144][40];
    int tid = threadIdx.x;
    const f16* src = qkv + (size_t)blockIdx.x * 36 * 192;
    for (int i = tid; i < 864; i += 256) {
        int p = i / 24, seg = i % 24;
        *(f16x8*)(&t[p][seg * 8]) = *(const f16x8*)(src + p * 192 + seg * 8);
    }
    __syncthreads();
    for (int i = tid; i < 5184; i += 256) {
        int h = i / 1296, r = i % 1296, p = r / 36, p2 = r % 36;
        f16x8 qa = *(const f16x8*)(&t[p][h * 16]);
        f16x8 qb = *(const f16x8*)(&t[p][h * 16 + 8]);
        f16x8 ka = *(const f16x8*)(&t[p2][64 + h * 16]);
        f16x8 kb = *(const f16x8*)(&t[p2][64 + h * 16 + 8]);
        float s = 0.f;
#pragma unroll
        for (int j = 0; j < 8; j++)
            s += (float)qa[j] * (float)ka[j] + (float)qb[j] * (float)kb[j];
        att[h * 36 + p][p2] = (f16)s;
    }
    __syncthreads();
    if (tid < 144) {
        float mx = -1e30f;
        for (int j = 0; j < 36; j++) mx = fmaxf(mx, (float)att[tid][j]);
        float sum = 0.f; float e[36];
        for (int j = 0; j < 36; j++) { float v = __expf((float)att[tid][j] - mx); e[j] = v; sum += v; }
        float inv = 1.f / sum;
        for (int j = 0; j < 36; j++) att[tid][j] = (f16)(e[j] * inv);
    }
    __syncthreads();
    for (int i = tid; i < 1152; i += 256) {
        int p = i >> 5, cp = i & 31, c0 = cp * 2, h = c0 >> 4;
        const f16* ar = &att[h * 36 + p][0];
        float s0 = 0.f, s1 = 0.f;
        for (int p2 = 0; p2 < 36; p2++) {
            float a = (float)ar[p2];
            f16x2 vv = *(const f16x2*)(&t[p2][128 + c0]);
            s0 += a * (float)vv[0]; s1 += a * (float)vv[1];
        }
        f16x2 o; o[0] = (f16)s0; o[1] = (f16)s1;
        *(f16x2*)(attout + (size_t)blockIdx.x * 2304 + p * 64 + c0) = o;
    }
}

// ---------------- masked GRU scan: 16 co-resident blocks + grid barrier ----
__global__ __launch_bounds__(256) void k_gru(const float* __restrict__ GX,
                                             const float* __restrict__ done,
                                             const float* __restrict__ h0,
                                             const float* __restrict__ whh,
                                             const float* __restrict__ bhh,
                                             float* __restrict__ hs,
                                             unsigned* __restrict__ bar) {
    int blk = blockIdx.x;
    int d0 = blk * 8;
    __shared__ float wl[24][128];
    __shared__ float hbuf[32][132];
    for (int i = threadIdx.x; i < 24 * 128; i += 256) {
        int r = i / 128, k = i % 128;
        int g = r / 8, dl = r % 8;
        wl[r][k] = whh[(size_t)(g * 128 + d0 + dl) * 128 + k];
    }
    int b = threadIdx.x & 31, dl = threadIdx.x >> 5;
    int d = d0 + dl;
    float bh_r = bhh[d], bh_z = bhh[128 + d], bh_n = bhh[256 + d];
    for (int t = 0; t < 64; t++) {
        __syncthreads();
        const float* hsrc = (t == 0) ? h0 : (hs + (size_t)(t - 1) * 4096);
        for (int i = threadIdx.x; i < 4096; i += 256) {
            int bb = i >> 7, k = i & 127;
            float dt = done[t * 32 + bb];
            hbuf[bb][k] = hsrc[i] * (1.f - dt);
        }
        __syncthreads();
        const float4* h4 = (const float4*)(&hbuf[b][0]);
        const float4* wr4 = (const float4*)(&wl[dl][0]);
        const float4* wz4 = (const float4*)(&wl[8 + dl][0]);
        const float4* wn4 = (const float4*)(&wl[16 + dl][0]);
        float sr = bh_r, sz = bh_z, sn = bh_n;
#pragma unroll 8
        for (int k = 0; k < 32; k++) {
            float4 hv = h4[k];
            float4 a = wr4[k], bz = wz4[k], cn = wn4[k];
            sr += a.x * hv.x + a.y * hv.y + a.z * hv.z + a.w * hv.w;
            sz += bz.x * hv.x + bz.y * hv.y + bz.z * hv.z + bz.w * hv.w;
            sn += cn.x * hv.x + cn.y * hv.y + cn.z * hv.z + cn.w * hv.w;
        }
        const float* gx = GX + (size_t)(t * 32 + b) * 384;
        float xr = gx[d], xz = gx[128 + d], xn = gx[256 + d];
        float hc = hbuf[b][d];
        float rg = 1.f / (1.f + expf(-(xr + sr)));
        float zg = 1.f / (1.f + expf(-(xz + sz)));
        float ng = tanhf(xn + rg * sn);
        float hnew = (1.f - zg) * ng + zg * hc;
        hs[(size_t)t * 4096 + b * 128 + d] = hnew;
        __threadfence();
        __syncthreads();
        if (threadIdx.x == 0) {
            atomicAdd(bar, 1u);
            unsigned target = 16u * (unsigned)(t + 1);
            while (atomicAdd(bar, 0u) < target) { __builtin_amdgcn_s_sleep(2); }
            __threadfence();
        }
        __syncthreads();
    }
}

// ---------------- critic head ----------------
__global__ __launch_bounds__(256) void k_critic(const float* __restrict__ hs,
                                                const float* __restrict__ crw,
                                                const float* __restrict__ crb,
                                                float* __restrict__ out) {
    int wave = threadIdx.x >> 6, lane = threadIdx.x & 63;
    int row = blockIdx.x * 4 + wave;
    const float* hr = hs + (size_t)row * 128;
    float s = hr[lane] * crw[lane] + hr[64 + lane] * crw[64 + lane];
#pragma unroll
    for (int off = 32; off; off >>= 1) s += __shfl_down(s, off);
    if (lane == 0) out[row] = s + crb[0];
}

extern "C" void kernel_launch(void* const* d_in, const int* in_sizes, int n_in,
                              void* d_out, int out_size, void* d_ws, size_t ws_size,
                              hipStream_t stream) {
    const float* x     = (const float*)d_in[0];
    const float* done  = (const float*)d_in[1];
    const float* gru0  = (const float*)d_in[2];
    const float* c1w   = (const float*)d_in[3];
    const float* c1b   = (const float*)d_in[4];
    const float* c2w   = (const float*)d_in[5];
    const float* c2b   = (const float*)d_in[6];
    const float* c3w   = (const float*)d_in[7];
    const float* c3b   = (const float*)d_in[8];
    const float* fc1w  = (const float*)d_in[9];
    const float* fc2w  = (const float*)d_in[10];
    const float* spw   = (const float*)d_in[11];
    const float* qkvw  = (const float*)d_in[12];
    const float* projw = (const float*)d_in[13];
    const float* projb = (const float*)d_in[14];
    const float* fcw   = (const float*)d_in[15];
    const float* fcb   = (const float*)d_in[16];
    const float* wih   = (const float*)d_in[17];
    const float* whh   = (const float*)d_in[18];
    const float* bih   = (const float*)d_in[19];
    const float* bhh   = (const float*)d_in[20];
    const float* crw   = (const float*)d_in[21];
    const float* crb   = (const float*)d_in[22];
    float* out = (float*)d_out;

    f16* h1   = (f16*)d_ws;                 // 2048*784*32
    f16* h2   = h1 + 51380224ull;           // 2048*169*64
    f16* h3   = h2 + 22151168ull;           // 2048*36*64
    f16* f256 = h3 + 4718592ull;            // 2048*256
    f16* W1   = f256 + 524288ull;           // 8192
    f16* W2   = W1 + 8192;                  // 32768
    f16* W3   = W2 + 32768;                 // 36864
    f16* FCW  = W3 + 36864;                 // 589824
    f16* WIH  = FCW + 589824;               // 98304
    f16* QKVW = WIH + 98304;                // 12288
    f16* PROJW = QKVW + 12288;              // 4096
    float* zb  = (float*)(PROJW + 4096);    // 192 zero bias
    float* gxb = zb + 192;                  // 2048*384 fp32
    float* hsb = gxb + 786432;              // 64*32*128 fp32
    unsigned* bar = (unsigned*)(hsb + 262144);
    // h1 is dead after conv2 -> reuse for qkv / attout
    f16* qkv    = h1;                       // 73728*192
    f16* attout = h1 + 14155776ull;         // 73728*64

    k_prep<<<3056, 256, 0, stream>>>(c1w, c2w, c3w, fcw, wih, qkvw, projw,
                                     W1, W2, W3, FCW, WIH, QKVW, PROJW);
    hipMemsetAsync(bar, 0, 16, stream);
    hipMemsetAsync(zb, 0, 768, stream);

    k_conv<4, 8, 8, 4, 116, 28, 784, 32, true><<<25088, 256, 0, stream>>>(x, W1, c1b, h1);
    k_conv<32, 4, 4, 2, 28, 13, 169, 64, false><<<5408, 256, 0, stream>>>(h1, W2, c2b, h2);
    k_conv<64, 3, 3, 2, 13, 6, 36, 64, false><<<1152, 256, 0, stream>>>(h2, W3, c3b, h3);
    k_gate<<<512, 256, 0, stream>>>(h3, fc1w, fc2w, spw);
    // qkv = h3_gated @ QKVW^T  (M=73728, N=192, K=64)
    k_gemm16<false, false, false><<<dim3(3, 1152), 256, 0, stream>>>(h3, QKVW, zb, nullptr, qkv, 192, 64);
    k_attn<<<2048, 256, 0, stream>>>(qkv, attout);
    // h3 = attout @ PROJW^T + projb + h3  (residual fused)
    k_gemm16<false, false, true><<<dim3(1, 1152), 256, 0, stream>>>(attout, PROJW, projb, h3, h3, 64, 64);
    k_gemm16<true, false, false><<<dim3(4, 32), 256, 0, stream>>>(h3, FCW, fcb, nullptr, f256, 256, 2304);
    k_gemm16<false, true, false><<<dim3(6, 32), 256, 0, stream>>>(f256, WIH, bih, nullptr, gxb, 384, 256);
    k_gru<<<16, 256, 0, stream>>>(gxb, done, gru0, whh, bhh, hsb, bar);
    k_critic<<<512, 256, 0, stream>>>(hsb, crw, crb, out);
}

// Round 2
// 1089.030 us; speedup vs baseline: 1.6169x; 1.2993x over previous
//
#include <hip/hip_runtime.h>
#include <math.h>

typedef _Float16 f16;
typedef f16 f16x8 __attribute__((ext_vector_type(8)));
typedef f16 f16x2 __attribute__((ext_vector_type(2)));
typedef float f32x4 __attribute__((ext_vector_type(4)));

// ---------------- weight prep: fp32 -> fp16, conv weights to [n][k] with
// k-order matching the conv A-staging chunk layout ----------------
__global__ __launch_bounds__(256) void k_prep(const float* __restrict__ c1w,
                                              const float* __restrict__ c2w,
                                              const float* __restrict__ c3w,
                                              const float* __restrict__ fcw,
                                              const float* __restrict__ wih,
                                              const float* __restrict__ qkvw,
                                              const float* __restrict__ projw,
                                              f16* __restrict__ W1, f16* __restrict__ W2,
                                              f16* __restrict__ W3, f16* __restrict__ FCW,
                                              f16* __restrict__ WIH, f16* __restrict__ QKVW,
                                              f16* __restrict__ PROJW) {
    int i0 = blockIdx.x * 256 + threadIdx.x;
    if (i0 < 8192) {                       // conv1: k = kh*32 + c*8 + kw
        int n = i0 >> 8, k = i0 & 255;
        int kh = k >> 5, r = k & 31, c = r >> 3, kw = r & 7;
        W1[i0] = (f16)c1w[((n * 4 + c) * 8 + kh) * 8 + kw];
    } else if (i0 < 8192 + 32768) {        // conv2: k = kh*128 + kw*32 + c
        int i = i0 - 8192;
        int n = i >> 9, k = i & 511;
        int kh = k >> 7, r = k & 127, kw = r >> 5, c = r & 31;
        W2[i] = (f16)c2w[((n * 32 + c) * 4 + kh) * 4 + kw];
    } else if (i0 < 8192 + 32768 + 36864) {  // conv3: k = kh*192 + kw*64 + c
        int i = i0 - (8192 + 32768);
        int n = i / 576, k = i % 576;
        int kh = k / 192, r = k % 192, kw = r / 64, c = r & 63;
        W3[i] = (f16)c3w[((n * 64 + c) * 3 + kh) * 3 + kw];
    } else if (i0 < 8192 + 32768 + 36864 + 589824) {  // FC: k = p*64 + c (NHWC flat)
        int i = i0 - (8192 + 32768 + 36864);
        int o = i / 2304, k = i % 2304, p = k >> 6, c = k & 63;
        FCW[i] = (f16)fcw[o * 2304 + c * 36 + p];
    } else if (i0 < 765952) {
        int i = i0 - (8192 + 32768 + 36864 + 589824);
        WIH[i] = (f16)wih[i];
    } else if (i0 < 765952 + 12288) {      // qkv weight, q rows pre-scaled by 0.25
        int i = i0 - 765952;
        QKVW[i] = (f16)(qkvw[i] * ((i < 4096) ? 0.25f : 1.f));
    } else if (i0 < 765952 + 12288 + 4096) {
        int i = i0 - (765952 + 12288);
        PROJW[i] = (f16)projw[i];
    }
}

// ---------------- implicit-GEMM MFMA conv (NHWC fp16 in/out, ReLU) --------
template <int CINP, int KH, int KW, int STRIDE, int IW, int OW, int PPI, int NCH, bool SRCF32>
__global__ __launch_bounds__(256) void k_conv(const void* __restrict__ srcv,
                                              const f16* __restrict__ W,  // [NCH][KH*CK]
                                              const float* __restrict__ bias,
                                              f16* __restrict__ dst) {
    constexpr int CK = KW * CINP;
    constexpr int KS = CK / 32;
    constexpr int NT = NCH / 16;
    constexpr int LA = CK + 8;
    constexpr int AUN = SRCF32 ? 64 * CINP : (64 * CK) / 8;
    constexpr int WUN = (NCH * CK) / 8;
    constexpr int ANU = (AUN + 255) / 256;
    constexpr int WNU = (WUN + 255) / 256;
    __shared__ f16 As[64 * LA];
    __shared__ f16 Bs[NCH * LA];
    const int tid = threadIdx.x;
    const int wave = tid >> 6, lane = tid & 63;
    const int m0 = blockIdx.x * 64;

    int aGB[ANU], aLO[ANU];
#pragma unroll
    for (int j = 0; j < ANU; j++) {
        int u = tid + j * 256;
        if (u < AUN) {
            if (SRCF32) {
                int px = u / CINP, c = u % CINP;
                int m = m0 + px, n = m / PPI, pp = m % PPI, oy = pp / OW, ox = pp % OW;
                aGB[j] = ((n * CINP + c) * IW + oy * STRIDE) * IW + ox * STRIDE;
                aLO[j] = px * LA + c * 8;
            } else {
                constexpr int SPP = CK / 8;
                int px = u / SPP, seg = u % SPP;
                int m = m0 + px, n = m / PPI, pp = m % PPI, oy = pp / OW, ox = pp % OW;
                aGB[j] = ((n * IW + oy * STRIDE) * IW + ox * STRIDE) * CINP + seg * 8;
                aLO[j] = px * LA + seg * 8;
            }
        }
    }
    int wGB[WNU], wLO[WNU];
#pragma unroll
    for (int j = 0; j < WNU; j++) {
        int u = tid + j * 256;
        if (u < WUN) {
            constexpr int SPP = CK / 8;
            int n = u / SPP, seg = u % SPP;
            wGB[j] = n * (KH * CK) + seg * 8;
            wLO[j] = n * LA + seg * 8;
        }
    }

    f32x4 acc[NT] = {};
    const f16* ap = As + (wave * 16 + (lane & 15)) * LA + (lane >> 4) * 8;
    const f16* bp = Bs + (lane & 15) * LA + (lane >> 4) * 8;

    for (int kh = 0; kh < KH; kh++) {
        __syncthreads();
#pragma unroll
        for (int j = 0; j < ANU; j++) {
            int u = tid + j * 256;
            if (u < AUN) {
                if (SRCF32) {
                    const float* s = (const float*)srcv + aGB[j] + kh * IW;
                    float4 v0 = *(const float4*)s;
                    float4 v1 = *(const float4*)(s + 4);
                    f16x8 h;
                    h[0] = (f16)v0.x; h[1] = (f16)v0.y; h[2] = (f16)v0.z; h[3] = (f16)v0.w;
                    h[4] = (f16)v1.x; h[5] = (f16)v1.y; h[6] = (f16)v1.z; h[7] = (f16)v1.w;
                    *(f16x8*)(As + aLO[j]) = h;
                } else {
                    const f16* s = (const f16*)srcv + aGB[j] + kh * (IW * CINP);
                    *(f16x8*)(As + aLO[j]) = *(const f16x8*)s;
                }
            }
        }
#pragma unroll
        for (int j = 0; j < WNU; j++) {
            int u = tid + j * 256;
            if (u < WUN)
                *(f16x8*)(Bs + wLO[j]) = *(const f16x8*)(W + wGB[j] + kh * CK);
        }
        __syncthreads();
#pragma unroll
        for (int ks = 0; ks < KS; ks++) {
            f16x8 af = *(const f16x8*)(ap + ks * 32);
#pragma unroll
            for (int nt = 0; nt < NT; nt++) {
                f16x8 bf = *(const f16x8*)(bp + nt * 16 * LA + ks * 32);
                acc[nt] = __builtin_amdgcn_mfma_f32_16x16x32_f16(af, bf, acc[nt], 0, 0, 0);
            }
        }
    }
    __syncthreads();
    {
        int rrow = wave * 16 + ((lane >> 4) << 2);
        int col = lane & 15;
#pragma unroll
        for (int nt = 0; nt < NT; nt++) {
            float bb = bias[nt * 16 + col];
#pragma unroll
            for (int r = 0; r < 4; r++) {
                float v = acc[nt][r] + bb;
                As[(rrow + r) * NCH + nt * 16 + col] = (f16)fmaxf(v, 0.f);
            }
        }
    }
    __syncthreads();
    constexpr int OUN = 64 * NCH / 8;
    for (int u = tid; u < OUN; u += 256) {
        int px = u / (NCH / 8), seg = u % (NCH / 8);
        *(f16x8*)(dst + (size_t)(m0 + px) * NCH + seg * 8) = *(const f16x8*)(As + px * NCH + seg * 8);
    }
}

// ---------------- MFMA GEMM: C = act(A(MxK,f16) @ W(NxK,f16)^T + bias [+ R]) ----
template <bool RELU, bool OUTF32, bool RESID>
__global__ __launch_bounds__(256) void k_gemm16(const f16* __restrict__ A,
                                                const f16* __restrict__ W,
                                                const float* __restrict__ bias,
                                                const f16* __restrict__ R,
                                                void* __restrict__ Cv, int N, int K) {
    __shared__ f16 As[64 * 72];
    __shared__ f16 Bs[64 * 72];
    int tid = threadIdx.x, wave = tid >> 6, lane = tid & 63;
    int n0 = blockIdx.x * 64, m0 = blockIdx.y * 64;
    f32x4 acc[4] = {};
    const f16* ap = As + (wave * 16 + (lane & 15)) * 72 + (lane >> 4) * 8;
    const f16* bp = Bs + (lane & 15) * 72 + (lane >> 4) * 8;
    int arow = tid >> 3, aseg = tid & 7;
    for (int k0 = 0; k0 < K; k0 += 64) {
        __syncthreads();
        *(f16x8*)(As + arow * 72 + aseg * 8) = *(const f16x8*)(A + (size_t)(m0 + arow) * K + k0 + aseg * 8);
        *(f16x8*)(As + (arow + 32) * 72 + aseg * 8) = *(const f16x8*)(A + (size_t)(m0 + arow + 32) * K + k0 + aseg * 8);
        *(f16x8*)(Bs + arow * 72 + aseg * 8) = *(const f16x8*)(W + (size_t)(n0 + arow) * K + k0 + aseg * 8);
        *(f16x8*)(Bs + (arow + 32) * 72 + aseg * 8) = *(const f16x8*)(W + (size_t)(n0 + arow + 32) * K + k0 + aseg * 8);
        __syncthreads();
#pragma unroll
        for (int ks = 0; ks < 2; ks++) {
            f16x8 af = *(const f16x8*)(ap + ks * 32);
#pragma unroll
            for (int nt = 0; nt < 4; nt++) {
                f16x8 bf = *(const f16x8*)(bp + nt * 16 * 72 + ks * 32);
                acc[nt] = __builtin_amdgcn_mfma_f32_16x16x32_f16(af, bf, acc[nt], 0, 0, 0);
            }
        }
    }
    int mrow = m0 + wave * 16 + ((lane >> 4) << 2);
    int col = n0 + (lane & 15);
#pragma unroll
    for (int nt = 0; nt < 4; nt++) {
        float bb = bias[col + nt * 16];
#pragma unroll
        for (int r = 0; r < 4; r++) {
            float v = acc[nt][r] + bb;
            if (RESID) v += (float)R[(size_t)(mrow + r) * N + col + nt * 16];
            if (RELU) v = fmaxf(v, 0.f);
            if (OUTF32) ((float*)Cv)[(size_t)(mrow + r) * N + col + nt * 16] = v;
            else ((f16*)Cv)[(size_t)(mrow + r) * N + col + nt * 16] = (f16)v;
        }
    }
}

// ---------------- CBAM channel+spatial gates, in-place on NHWC fp16 h3 ----
__global__ __launch_bounds__(256) void k_gate(f16* __restrict__ h3,
                                              const float* __restrict__ fc1w,
                                              const float* __restrict__ fc2w,
                                              const float* __restrict__ spw) {
    __shared__ float tok[4][36][67];
    __shared__ float pm[4][64], px[4][64], hml[4][32], chv[4][64];
    __shared__ float spm[4][36], spx[4][36], gsp[4][36];
    int s = threadIdx.x >> 6, lane = threadIdx.x & 63;
    f16* hb = h3 + (size_t)(blockIdx.x * 4 + s) * 2304;
    for (int i = lane; i < 2304; i += 64) tok[s][i >> 6][i & 63] = (float)hb[i];
    __syncthreads();
    {
        float m = 0.f, mx = -1e30f;
        for (int p = 0; p < 36; p++) { float v = tok[s][p][lane]; m += v; mx = fmaxf(mx, v); }
        pm[s][lane] = m * (1.f / 36.f); px[s][lane] = mx;
    }
    __syncthreads();
    if (lane < 32) {
        int j = lane & 15;
        const float* srcv = (lane < 16) ? pm[s] : px[s];
        float acc = 0.f;
        for (int c = 0; c < 64; c++) acc += fc1w[j * 64 + c] * srcv[c];
        hml[s][lane] = fmaxf(acc, 0.f);
    }
    __syncthreads();
    {
        float acc = 0.f;
        for (int j = 0; j < 16; j++) acc += fc2w[lane * 16 + j] * (hml[s][j] + hml[s][16 + j]);
        chv[s][lane] = 1.f / (1.f + expf(-acc));
    }
    __syncthreads();
    if (lane < 36) {
        float m = 0.f, mx = -1e30f;
        for (int c = 0; c < 64; c++) {
            float v = tok[s][lane][c] * chv[s][c];
            tok[s][lane][c] = v; m += v; mx = fmaxf(mx, v);
        }
        spm[s][lane] = m * (1.f / 64.f); spx[s][lane] = mx;
    }
    __syncthreads();
    if (lane < 36) {
        int y = lane / 6, x = lane % 6;
        float acc = 0.f;
        for (int dy = 0; dy < 7; dy++) {
            int yy = y + dy - 3; if (yy < 0 || yy > 5) continue;
            for (int dx = 0; dx < 7; dx++) {
                int xx = x + dx - 3; if (xx < 0 || xx > 5) continue;
                int pp = yy * 6 + xx;
                acc += spw[dy * 7 + dx] * spm[s][pp] + spw[49 + dy * 7 + dx] * spx[s][pp];
            }
        }
        gsp[s][lane] = 1.f / (1.f + expf(-acc));
    }
    __syncthreads();
    for (int i = lane; i < 2304; i += 64) {
        int p = i >> 6;
        hb[i] = (f16)(tok[s][p][i & 63] * gsp[s][p]);
    }
}

// ---------------- per-sample attention core: scores -> softmax -> PV ------
__global__ __launch_bounds__(256) void k_attn(const f16* __restrict__ qkv,
                                              f16* __restrict__ attout) {
    __shared__ f16 t[36][200];
    __shared__ f16 att[144][40];
    int tid = threadIdx.x;
    const f16* src = qkv + (size_t)blockIdx.x * 36 * 192;
    for (int i = tid; i < 864; i += 256) {
        int p = i / 24, seg = i % 24;
        *(f16x8*)(&t[p][seg * 8]) = *(const f16x8*)(src + p * 192 + seg * 8);
    }
    __syncthreads();
    for (int i = tid; i < 5184; i += 256) {
        int h = i / 1296, r = i % 1296, p = r / 36, p2 = r % 36;
        f16x8 qa = *(const f16x8*)(&t[p][h * 16]);
        f16x8 qb = *(const f16x8*)(&t[p][h * 16 + 8]);
        f16x8 ka = *(const f16x8*)(&t[p2][64 + h * 16]);
        f16x8 kb = *(const f16x8*)(&t[p2][64 + h * 16 + 8]);
        float s = 0.f;
#pragma unroll
        for (int j = 0; j < 8; j++)
            s += (float)qa[j] * (float)ka[j] + (float)qb[j] * (float)kb[j];
        att[h * 36 + p][p2] = (f16)s;
    }
    __syncthreads();
    if (tid < 144) {
        float mx = -1e30f;
        for (int j = 0; j < 36; j++) mx = fmaxf(mx, (float)att[tid][j]);
        float sum = 0.f; float e[36];
        for (int j = 0; j < 36; j++) { float v = __expf((float)att[tid][j] - mx); e[j] = v; sum += v; }
        float inv = 1.f / sum;
        for (int j = 0; j < 36; j++) att[tid][j] = (f16)(e[j] * inv);
    }
    __syncthreads();
    for (int i = tid; i < 1152; i += 256) {
        int p = i >> 5, cp = i & 31, c0 = cp * 2, h = c0 >> 4;
        const f16* ar = &att[h * 36 + p][0];
        float s0 = 0.f, s1 = 0.f;
        for (int p2 = 0; p2 < 36; p2++) {
            float a = (float)ar[p2];
            f16x2 vv = *(const f16x2*)(&t[p2][128 + c0]);
            s0 += a * (float)vv[0]; s1 += a * (float)vv[1];
        }
        f16x2 o; o[0] = (f16)s0; o[1] = (f16)s1;
        *(f16x2*)(attout + (size_t)blockIdx.x * 2304 + p * 64 + c0) = o;
    }
}

// ---------------- masked GRU scan: 2 blocks x 16 batches, no grid sync ----
// B-frags of whh live in registers (f16); hidden state double-buffered fp32 in LDS.
__global__ __launch_bounds__(256, 1) void k_gru(const float* __restrict__ GX,
                                                const float* __restrict__ done,
                                                const float* __restrict__ h0,
                                                const float* __restrict__ whh,
                                                const float* __restrict__ bhh,
                                                float* __restrict__ hs) {
    __shared__ float hlds[2][16][132];
    __shared__ float dlds[2048];
    const int tid = threadIdx.x;
    const int wave = tid >> 6, lane = tid & 63;
    const int lr = lane & 15, lq = lane >> 4;
    const int b0 = blockIdx.x * 16;

    for (int i = tid; i < 2048; i += 256) dlds[i] = done[i];
    for (int i = tid; i < 2048; i += 256) hlds[0][i >> 7][i & 127] = h0[(size_t)b0 * 128 + i];

    // B-frags: wf[j][ks] <- whh row n = (wave+4j)*16+lr, k = ks*32 + lq*8
    // j = gate*2 + dimhalf: tiles {w, w+4}=r, {w+8, w+12}=z, {w+16, w+20}=n
    f16x8 wf[6][4];
#pragma unroll
    for (int j = 0; j < 6; j++) {
        int n = (wave + 4 * j) * 16 + lr;
#pragma unroll
        for (int ks = 0; ks < 4; ks++) {
            const float* s = whh + (size_t)n * 128 + ks * 32 + lq * 8;
            float4 v0 = *(const float4*)s, v1 = *(const float4*)(s + 4);
            f16x8 h;
            h[0] = (f16)v0.x; h[1] = (f16)v0.y; h[2] = (f16)v0.z; h[3] = (f16)v0.w;
            h[4] = (f16)v1.x; h[5] = (f16)v1.y; h[6] = (f16)v1.z; h[7] = (f16)v1.w;
            wf[j][ks] = h;
        }
    }
    float bh[3][2];
#pragma unroll
    for (int g = 0; g < 3; g++)
#pragma unroll
        for (int hh = 0; hh < 2; hh++)
            bh[g][hh] = bhh[g * 128 + (wave + 4 * hh) * 16 + lr];

    int cur = 0;
    for (int t = 0; t < 64; t++) {
        __syncthreads();
        // gx loads for this step's epilogue — issue early, latency hides under MFMA
        float px[2][4][3];
#pragma unroll
        for (int hh = 0; hh < 2; hh++) {
            int d = (wave + 4 * hh) * 16 + lr;
#pragma unroll
            for (int r = 0; r < 4; r++) {
                const float* g = GX + (size_t)(t * 32 + b0 + lq * 4 + r) * 384 + d;
                px[hh][r][0] = g[0]; px[hh][r][1] = g[128]; px[hh][r][2] = g[256];
            }
        }
        float dtA = 1.f - dlds[t * 32 + b0 + lr];
        f16x8 af[4];
#pragma unroll
        for (int ks = 0; ks < 4; ks++) {
            const float* hr = &hlds[cur][lr][ks * 32 + lq * 8];
            float4 v0 = *(const float4*)hr, v1 = *(const float4*)(hr + 4);
            f16x8 h;
            h[0] = (f16)(v0.x * dtA); h[1] = (f16)(v0.y * dtA);
            h[2] = (f16)(v0.z * dtA); h[3] = (f16)(v0.w * dtA);
            h[4] = (f16)(v1.x * dtA); h[5] = (f16)(v1.y * dtA);
            h[6] = (f16)(v1.z * dtA); h[7] = (f16)(v1.w * dtA);
            af[ks] = h;
        }
        float dtb[4];
#pragma unroll
        for (int r = 0; r < 4; r++) dtb[r] = 1.f - dlds[t * 32 + b0 + lq * 4 + r];
        float hcm[2][4];
#pragma unroll
        for (int hh = 0; hh < 2; hh++) {
            int d = (wave + 4 * hh) * 16 + lr;
#pragma unroll
            for (int r = 0; r < 4; r++)
                hcm[hh][r] = hlds[cur][lq * 4 + r][d] * dtb[r];
        }
        f32x4 acc[6] = {};
#pragma unroll
        for (int ks = 0; ks < 4; ks++) {
#pragma unroll
            for (int j = 0; j < 6; j++)
                acc[j] = __builtin_amdgcn_mfma_f32_16x16x32_f16(af[ks], wf[j][ks], acc[j], 0, 0, 0);
        }
        int nxt = cur ^ 1;
#pragma unroll
        for (int hh = 0; hh < 2; hh++) {
            int d = (wave + 4 * hh) * 16 + lr;
#pragma unroll
            for (int r = 0; r < 4; r++) {
                float sr = acc[0 + hh][r] + bh[0][hh];
                float sz = acc[2 + hh][r] + bh[1][hh];
                float sn = acc[4 + hh][r] + bh[2][hh];
                float rg = 1.f / (1.f + __expf(-(px[hh][r][0] + sr)));
                float zg = 1.f / (1.f + __expf(-(px[hh][r][1] + sz)));
                float a = px[hh][r][2] + rg * sn;
                float ng = 2.f / (1.f + __expf(-2.f * a)) - 1.f;   // tanh, saturates safely
                float hnew = (1.f - zg) * ng + zg * hcm[hh][r];
                hlds[nxt][lq * 4 + r][d] = hnew;
                hs[(size_t)(t * 32 + b0 + lq * 4 + r) * 128 + d] = hnew;
            }
        }
        cur = nxt;
    }
}

// ---------------- critic head ----------------
__global__ __launch_bounds__(256) void k_critic(const float* __restrict__ hs,
                                                const float* __restrict__ crw,
                                                const float* __restrict__ crb,
                                                float* __restrict__ out) {
    int wave = threadIdx.x >> 6, lane = threadIdx.x & 63;
    int row = blockIdx.x * 4 + wave;
    const float* hr = hs + (size_t)row * 128;
    float s = hr[lane] * crw[lane] + hr[64 + lane] * crw[64 + lane];
#pragma unroll
    for (int off = 32; off; off >>= 1) s += __shfl_down(s, off);
    if (lane == 0) out[row] = s + crb[0];
}

extern "C" void kernel_launch(void* const* d_in, const int* in_sizes, int n_in,
                              void* d_out, int out_size, void* d_ws, size_t ws_size,
                              hipStream_t stream) {
    const float* x     = (const float*)d_in[0];
    const float* done  = (const float*)d_in[1];
    const float* gru0  = (const float*)d_in[2];
    const float* c1w   = (const float*)d_in[3];
    const float* c1b   = (const float*)d_in[4];
    const float* c2w   = (const float*)d_in[5];
    const float* c2b   = (const float*)d_in[6];
    const float* c3w   = (const float*)d_in[7];
    const float* c3b   = (const float*)d_in[8];
    const float* fc1w  = (const float*)d_in[9];
    const float* fc2w  = (const float*)d_in[10];
    const float* spw   = (const float*)d_in[11];
    const float* qkvw  = (const float*)d_in[12];
    const float* projw = (const float*)d_in[13];
    const float* projb = (const float*)d_in[14];
    const float* fcw   = (const float*)d_in[15];
    const float* fcb   = (const float*)d_in[16];
    const float* wih   = (const float*)d_in[17];
    const float* whh   = (const float*)d_in[18];
    const float* bih   = (const float*)d_in[19];
    const float* bhh   = (const float*)d_in[20];
    const float* crw   = (const float*)d_in[21];
    const float* crb   = (const float*)d_in[22];
    float* out = (float*)d_out;

    f16* h1   = (f16*)d_ws;                 // 2048*784*32
    f16* h2   = h1 + 51380224ull;           // 2048*169*64
    f16* h3   = h2 + 22151168ull;           // 2048*36*64
    f16* f256 = h3 + 4718592ull;            // 2048*256
    f16* W1   = f256 + 524288ull;           // 8192
    f16* W2   = W1 + 8192;                  // 32768
    f16* W3   = W2 + 32768;                 // 36864
    f16* FCW  = W3 + 36864;                 // 589824
    f16* WIH  = FCW + 589824;               // 98304
    f16* QKVW = WIH + 98304;                // 12288
    f16* PROJW = QKVW + 12288;              // 4096
    float* zb  = (float*)(PROJW + 4096);    // 192 zero bias
    float* gxb = zb + 192;                  // 2048*384 fp32
    float* hsb = gxb + 786432;              // 64*32*128 fp32
    // h1 is dead after conv2 -> reuse for qkv / attout
    f16* qkv    = h1;                       // 73728*192
    f16* attout = h1 + 14155776ull;         // 73728*64

    k_prep<<<3056, 256, 0, stream>>>(c1w, c2w, c3w, fcw, wih, qkvw, projw,
                                     W1, W2, W3, FCW, WIH, QKVW, PROJW);
    hipMemsetAsync(zb, 0, 768, stream);

    k_conv<4, 8, 8, 4, 116, 28, 784, 32, true><<<25088, 256, 0, stream>>>(x, W1, c1b, h1);
    k_conv<32, 4, 4, 2, 28, 13, 169, 64, false><<<5408, 256, 0, stream>>>(h1, W2, c2b, h2);
    k_conv<64, 3, 3, 2, 13, 6, 36, 64, false><<<1152, 256, 0, stream>>>(h2, W3, c3b, h3);
    k_gate<<<512, 256, 0, stream>>>(h3, fc1w, fc2w, spw);
    // qkv = h3_gated @ QKVW^T  (M=73728, N=192, K=64)
    k_gemm16<false, false, false><<<dim3(3, 1152), 256, 0, stream>>>(h3, QKVW, zb, nullptr, qkv, 192, 64);
    k_attn<<<2048, 256, 0, stream>>>(qkv, attout);
    // h3 = attout @ PROJW^T + projb + h3  (residual fused)
    k_gemm16<false, false, true><<<dim3(1, 1152), 256, 0, stream>>>(attout, PROJW, projb, h3, h3, 64, 64);
    k_gemm16<true, false, false><<<dim3(4, 32), 256, 0, stream>>>(h3, FCW, fcb, nullptr, f256, 256, 2304);
    k_gemm16<false, true, false><<<dim3(6, 32), 256, 0, stream>>>(f256, WIH, bih, nullptr, gxb, 384, 256);
    k_gru<<<2, 256, 0, stream>>>(gxb, done, gru0, whh, bhh, hsb);
    k_critic<<<512, 256, 0, stream>>>(hsb, crw, crb, out);
}

// Round 3
// 1077.870 us; speedup vs baseline: 1.6337x; 1.0104x over previous
//
#include <hip/hip_runtime.h>
#include <math.h>

typedef _Float16 f16;
typedef f16 f16x8 __attribute__((ext_vector_type(8)));
typedef f16 f16x2 __attribute__((ext_vector_type(2)));
typedef float f32x4 __attribute__((ext_vector_type(4)));

// ---------------- weight prep: fp32 -> fp16, conv weights to [n][k] with
// k-order matching the conv A-staging chunk layout ----------------
__global__ __launch_bounds__(256) void k_prep(const float* __restrict__ c1w,
                                              const float* __restrict__ c2w,
                                              const float* __restrict__ c3w,
                                              const float* __restrict__ fcw,
                                              const float* __restrict__ wih,
                                              const float* __restrict__ qkvw,
                                              const float* __restrict__ projw,
                                              f16* __restrict__ W1, f16* __restrict__ W2,
                                              f16* __restrict__ W3, f16* __restrict__ FCW,
                                              f16* __restrict__ WIH, f16* __restrict__ QKVW,
                                              f16* __restrict__ PROJW) {
    int i0 = blockIdx.x * 256 + threadIdx.x;
    if (i0 < 8192) {                       // conv1: k = kh*32 + c*8 + kw
        int n = i0 >> 8, k = i0 & 255;
        int kh = k >> 5, r = k & 31, c = r >> 3, kw = r & 7;
        W1[i0] = (f16)c1w[((n * 4 + c) * 8 + kh) * 8 + kw];
    } else if (i0 < 8192 + 32768) {        // conv2: k = kh*128 + kw*32 + c
        int i = i0 - 8192;
        int n = i >> 9, k = i & 511;
        int kh = k >> 7, r = k & 127, kw = r >> 5, c = r & 31;
        W2[i] = (f16)c2w[((n * 32 + c) * 4 + kh) * 4 + kw];
    } else if (i0 < 8192 + 32768 + 36864) {  // conv3: k = kh*192 + kw*64 + c
        int i = i0 - (8192 + 32768);
        int n = i / 576, k = i % 576;
        int kh = k / 192, r = k % 192, kw = r / 64, c = r & 63;
        W3[i] = (f16)c3w[((n * 64 + c) * 3 + kh) * 3 + kw];
    } else if (i0 < 8192 + 32768 + 36864 + 589824) {  // FC: k = p*64 + c (NHWC flat)
        int i = i0 - (8192 + 32768 + 36864);
        int o = i / 2304, k = i % 2304, p = k >> 6, c = k & 63;
        FCW[i] = (f16)fcw[o * 2304 + c * 36 + p];
    } else if (i0 < 765952) {
        int i = i0 - (8192 + 32768 + 36864 + 589824);
        WIH[i] = (f16)wih[i];
    } else if (i0 < 765952 + 12288) {      // qkv weight, q rows pre-scaled by 0.25
        int i = i0 - 765952;
        QKVW[i] = (f16)(qkvw[i] * ((i < 4096) ? 0.25f : 1.f));
    } else if (i0 < 765952 + 12288 + 4096) {
        int i = i0 - (765952 + 12288);
        PROJW[i] = (f16)projw[i];
    }
}

// ---------------- implicit-GEMM MFMA conv (NHWC fp16 in/out, ReLU) --------
// XCD-aware chunked swizzle: consecutive work-tiles (same sample) -> same XCD L2.
template <int CINP, int KH, int KW, int STRIDE, int IW, int OW, int PPI, int NCH, bool SRCF32>
__global__ __launch_bounds__(256) void k_conv(const void* __restrict__ srcv,
                                              const f16* __restrict__ W,  // [NCH][KH*CK]
                                              const float* __restrict__ bias,
                                              f16* __restrict__ dst) {
    constexpr int CK = KW * CINP;
    constexpr int KS = CK / 32;
    constexpr int NT = NCH / 16;
    constexpr int LA = CK + 8;
    constexpr int AUN = SRCF32 ? 64 * CINP : (64 * CK) / 8;
    constexpr int WUN = (NCH * CK) / 8;
    constexpr int ANU = (AUN + 255) / 256;
    constexpr int WNU = (WUN + 255) / 256;
    __shared__ f16 As[64 * LA];
    __shared__ f16 Bs[NCH * LA];
    const int tid = threadIdx.x;
    const int wave = tid >> 6, lane = tid & 63;
    int bid = blockIdx.x;
    int nwg = gridDim.x;
    int swz = ((nwg & 7) == 0) ? ((bid & 7) * (nwg >> 3) + (bid >> 3)) : bid;
    const int m0 = swz * 64;

    int aGB[ANU], aLO[ANU];
#pragma unroll
    for (int j = 0; j < ANU; j++) {
        int u = tid + j * 256;
        if (u < AUN) {
            if (SRCF32) {
                int px = u / CINP, c = u % CINP;
                int m = m0 + px, n = m / PPI, pp = m % PPI, oy = pp / OW, ox = pp % OW;
                aGB[j] = ((n * CINP + c) * IW + oy * STRIDE) * IW + ox * STRIDE;
                aLO[j] = px * LA + c * 8;
            } else {
                constexpr int SPP = CK / 8;
                int px = u / SPP, seg = u % SPP;
                int m = m0 + px, n = m / PPI, pp = m % PPI, oy = pp / OW, ox = pp % OW;
                aGB[j] = ((n * IW + oy * STRIDE) * IW + ox * STRIDE) * CINP + seg * 8;
                aLO[j] = px * LA + seg * 8;
            }
        }
    }
    int wGB[WNU], wLO[WNU];
#pragma unroll
    for (int j = 0; j < WNU; j++) {
        int u = tid + j * 256;
        if (u < WUN) {
            constexpr int SPP = CK / 8;
            int n = u / SPP, seg = u % SPP;
            wGB[j] = n * (KH * CK) + seg * 8;
            wLO[j] = n * LA + seg * 8;
        }
    }

    f32x4 acc[NT] = {};
    const f16* ap = As + (wave * 16 + (lane & 15)) * LA + (lane >> 4) * 8;
    const f16* bp = Bs + (lane & 15) * LA + (lane >> 4) * 8;

    for (int kh = 0; kh < KH; kh++) {
        __syncthreads();
#pragma unroll
        for (int j = 0; j < ANU; j++) {
            int u = tid + j * 256;
            if (u < AUN) {
                if (SRCF32) {
                    const float* s = (const float*)srcv + aGB[j] + kh * IW;
                    float4 v0 = *(const float4*)s;
                    float4 v1 = *(const float4*)(s + 4);
                    f16x8 h;
                    h[0] = (f16)v0.x; h[1] = (f16)v0.y; h[2] = (f16)v0.z; h[3] = (f16)v0.w;
                    h[4] = (f16)v1.x; h[5] = (f16)v1.y; h[6] = (f16)v1.z; h[7] = (f16)v1.w;
                    *(f16x8*)(As + aLO[j]) = h;
                } else {
                    const f16* s = (const f16*)srcv + aGB[j] + kh * (IW * CINP);
                    *(f16x8*)(As + aLO[j]) = *(const f16x8*)s;
                }
            }
        }
#pragma unroll
        for (int j = 0; j < WNU; j++) {
            int u = tid + j * 256;
            if (u < WUN)
                *(f16x8*)(Bs + wLO[j]) = *(const f16x8*)(W + wGB[j] + kh * CK);
        }
        __syncthreads();
#pragma unroll
        for (int ks = 0; ks < KS; ks++) {
            f16x8 af = *(const f16x8*)(ap + ks * 32);
#pragma unroll
            for (int nt = 0; nt < NT; nt++) {
                f16x8 bf = *(const f16x8*)(bp + nt * 16 * LA + ks * 32);
                acc[nt] = __builtin_amdgcn_mfma_f32_16x16x32_f16(af, bf, acc[nt], 0, 0, 0);
            }
        }
    }
    __syncthreads();
    {
        int rrow = wave * 16 + ((lane >> 4) << 2);
        int col = lane & 15;
#pragma unroll
        for (int nt = 0; nt < NT; nt++) {
            float bb = bias[nt * 16 + col];
#pragma unroll
            for (int r = 0; r < 4; r++) {
                float v = acc[nt][r] + bb;
                As[(rrow + r) * NCH + nt * 16 + col] = (f16)fmaxf(v, 0.f);
            }
        }
    }
    __syncthreads();
    constexpr int OUN = 64 * NCH / 8;
    for (int u = tid; u < OUN; u += 256) {
        int px = u / (NCH / 8), seg = u % (NCH / 8);
        *(f16x8*)(dst + (size_t)(m0 + px) * NCH + seg * 8) = *(const f16x8*)(As + px * NCH + seg * 8);
    }
}

// ---------------- MFMA GEMM: C = act(A(MxK,f16) @ W(NxK,f16)^T + bias [+ R]) ----
template <bool RELU, bool OUTF32, bool RESID>
__global__ __launch_bounds__(256) void k_gemm16(const f16* __restrict__ A,
                                                const f16* __restrict__ W,
                                                const float* __restrict__ bias,
                                                const f16* __restrict__ R,
                                                void* __restrict__ Cv, int N, int K) {
    __shared__ f16 As[64 * 72];
    __shared__ f16 Bs[64 * 72];
    int tid = threadIdx.x, wave = tid >> 6, lane = tid & 63;
    int n0 = blockIdx.x * 64, m0 = blockIdx.y * 64;
    f32x4 acc[4] = {};
    const f16* ap = As + (wave * 16 + (lane & 15)) * 72 + (lane >> 4) * 8;
    const f16* bp = Bs + (lane & 15) * 72 + (lane >> 4) * 8;
    int arow = tid >> 3, aseg = tid & 7;
    for (int k0 = 0; k0 < K; k0 += 64) {
        __syncthreads();
        *(f16x8*)(As + arow * 72 + aseg * 8) = *(const f16x8*)(A + (size_t)(m0 + arow) * K + k0 + aseg * 8);
        *(f16x8*)(As + (arow + 32) * 72 + aseg * 8) = *(const f16x8*)(A + (size_t)(m0 + arow + 32) * K + k0 + aseg * 8);
        *(f16x8*)(Bs + arow * 72 + aseg * 8) = *(const f16x8*)(W + (size_t)(n0 + arow) * K + k0 + aseg * 8);
        *(f16x8*)(Bs + (arow + 32) * 72 + aseg * 8) = *(const f16x8*)(W + (size_t)(n0 + arow + 32) * K + k0 + aseg * 8);
        __syncthreads();
#pragma unroll
        for (int ks = 0; ks < 2; ks++) {
            f16x8 af = *(const f16x8*)(ap + ks * 32);
#pragma unroll
            for (int nt = 0; nt < 4; nt++) {
                f16x8 bf = *(const f16x8*)(bp + nt * 16 * 72 + ks * 32);
                acc[nt] = __builtin_amdgcn_mfma_f32_16x16x32_f16(af, bf, acc[nt], 0, 0, 0);
            }
        }
    }
    int mrow = m0 + wave * 16 + ((lane >> 4) << 2);
    int col = n0 + (lane & 15);
#pragma unroll
    for (int nt = 0; nt < 4; nt++) {
        float bb = bias[col + nt * 16];
#pragma unroll
        for (int r = 0; r < 4; r++) {
            float v = acc[nt][r] + bb;
            if (RESID) v += (float)R[(size_t)(mrow + r) * N + col + nt * 16];
            if (RELU) v = fmaxf(v, 0.f);
            if (OUTF32) ((float*)Cv)[(size_t)(mrow + r) * N + col + nt * 16] = v;
            else ((f16*)Cv)[(size_t)(mrow + r) * N + col + nt * 16] = (f16)v;
        }
    }
}

// ---------------- CBAM channel+spatial gates, in-place on NHWC fp16 h3 ----
__global__ __launch_bounds__(256) void k_gate(f16* __restrict__ h3,
                                              const float* __restrict__ fc1w,
                                              const float* __restrict__ fc2w,
                                              const float* __restrict__ spw) {
    __shared__ float tok[4][36][67];
    __shared__ float pm[4][64], px[4][64], hml[4][32], chv[4][64];
    __shared__ float spm[4][36], spx[4][36], gsp[4][36];
    int s = threadIdx.x >> 6, lane = threadIdx.x & 63;
    f16* hb = h3 + (size_t)(blockIdx.x * 4 + s) * 2304;
    for (int i = lane; i < 2304; i += 64) tok[s][i >> 6][i & 63] = (float)hb[i];
    __syncthreads();
    {
        float m = 0.f, mx = -1e30f;
        for (int p = 0; p < 36; p++) { float v = tok[s][p][lane]; m += v; mx = fmaxf(mx, v); }
        pm[s][lane] = m * (1.f / 36.f); px[s][lane] = mx;
    }
    __syncthreads();
    if (lane < 32) {
        int j = lane & 15;
        const float* srcv = (lane < 16) ? pm[s] : px[s];
        float acc = 0.f;
        for (int c = 0; c < 64; c++) acc += fc1w[j * 64 + c] * srcv[c];
        hml[s][lane] = fmaxf(acc, 0.f);
    }
    __syncthreads();
    {
        float acc = 0.f;
        for (int j = 0; j < 16; j++) acc += fc2w[lane * 16 + j] * (hml[s][j] + hml[s][16 + j]);
        chv[s][lane] = 1.f / (1.f + expf(-acc));
    }
    __syncthreads();
    if (lane < 36) {
        float m = 0.f, mx = -1e30f;
        for (int c = 0; c < 64; c++) {
            float v = tok[s][lane][c] * chv[s][c];
            tok[s][lane][c] = v; m += v; mx = fmaxf(mx, v);
        }
        spm[s][lane] = m * (1.f / 64.f); spx[s][lane] = mx;
    }
    __syncthreads();
    if (lane < 36) {
        int y = lane / 6, x = lane % 6;
        float acc = 0.f;
        for (int dy = 0; dy < 7; dy++) {
            int yy = y + dy - 3; if (yy < 0 || yy > 5) continue;
            for (int dx = 0; dx < 7; dx++) {
                int xx = x + dx - 3; if (xx < 0 || xx > 5) continue;
                int pp = yy * 6 + xx;
                acc += spw[dy * 7 + dx] * spm[s][pp] + spw[49 + dy * 7 + dx] * spx[s][pp];
            }
        }
        gsp[s][lane] = 1.f / (1.f + expf(-acc));
    }
    __syncthreads();
    for (int i = lane; i < 2304; i += 64) {
        int p = i >> 6;
        hb[i] = (f16)(tok[s][p][i & 63] * gsp[s][p]);
    }
}

// ---------------- per-sample attention core: scores -> softmax -> PV ------
__global__ __launch_bounds__(256) void k_attn(const f16* __restrict__ qkv,
                                              f16* __restrict__ attout) {
    __shared__ f16 t[36][200];
    __shared__ f16 att[144][40];
    int tid = threadIdx.x;
    const f16* src = qkv + (size_t)blockIdx.x * 36 * 192;
    for (int i = tid; i < 864; i += 256) {
        int p = i / 24, seg = i % 24;
        *(f16x8*)(&t[p][seg * 8]) = *(const f16x8*)(src + p * 192 + seg * 8);
    }
    __syncthreads();
    for (int i = tid; i < 5184; i += 256) {
        int h = i / 1296, r = i % 1296, p = r / 36, p2 = r % 36;
        f16x8 qa = *(const f16x8*)(&t[p][h * 16]);
        f16x8 qb = *(const f16x8*)(&t[p][h * 16 + 8]);
        f16x8 ka = *(const f16x8*)(&t[p2][64 + h * 16]);
        f16x8 kb = *(const f16x8*)(&t[p2][64 + h * 16 + 8]);
        float s = 0.f;
#pragma unroll
        for (int j = 0; j < 8; j++)
            s += (float)qa[j] * (float)ka[j] + (float)qb[j] * (float)kb[j];
        att[h * 36 + p][p2] = (f16)s;
    }
    __syncthreads();
    if (tid < 144) {
        float mx = -1e30f;
        for (int j = 0; j < 36; j++) mx = fmaxf(mx, (float)att[tid][j]);
        float sum = 0.f; float e[36];
        for (int j = 0; j < 36; j++) { float v = __expf((float)att[tid][j] - mx); e[j] = v; sum += v; }
        float inv = 1.f / sum;
        for (int j = 0; j < 36; j++) att[tid][j] = (f16)(e[j] * inv);
    }
    __syncthreads();
    for (int i = tid; i < 1152; i += 256) {
        int p = i >> 5, cp = i & 31, c0 = cp * 2, h = c0 >> 4;
        const f16* ar = &att[h * 36 + p][0];
        float s0 = 0.f, s1 = 0.f;
        for (int p2 = 0; p2 < 36; p2++) {
            float a = (float)ar[p2];
            f16x2 vv = *(const f16x2*)(&t[p2][128 + c0]);
            s0 += a * (float)vv[0]; s1 += a * (float)vv[1];
        }
        f16x2 o; o[0] = (f16)s0; o[1] = (f16)s1;
        *(f16x2*)(attout + (size_t)blockIdx.x * 2304 + p * 64 + c0) = o;
    }
}

// ---------------- masked GRU scan: 2 blocks x 16 batches, no grid sync ----
// B-frags of whh in registers (f16); hidden state double-buffered fp32 in LDS;
// gx loads software-pipelined one step ahead (named ping-pong buffers).
__global__ __launch_bounds__(256, 1) void k_gru(const float* __restrict__ GX,
                                                const float* __restrict__ done,
                                                const float* __restrict__ h0,
                                                const float* __restrict__ whh,
                                                const float* __restrict__ bhh,
                                                float* __restrict__ hs) {
    __shared__ float hlds[2][16][132];
    __shared__ float dlds[2048];
    const int tid = threadIdx.x;
    const int wave = tid >> 6, lane = tid & 63;
    const int lr = lane & 15, lq = lane >> 4;
    const int b0 = blockIdx.x * 16;

    for (int i = tid; i < 2048; i += 256) dlds[i] = done[i];
    for (int i = tid; i < 2048; i += 256) hlds[0][i >> 7][i & 127] = h0[(size_t)b0 * 128 + i];

    // B-frags: wf[j][ks] <- whh row n = (wave+4j)*16+lr, k = ks*32 + lq*8
    f16x8 wf[6][4];
#pragma unroll
    for (int j = 0; j < 6; j++) {
        int n = (wave + 4 * j) * 16 + lr;
#pragma unroll
        for (int ks = 0; ks < 4; ks++) {
            const float* s = whh + (size_t)n * 128 + ks * 32 + lq * 8;
            float4 v0 = *(const float4*)s, v1 = *(const float4*)(s + 4);
            f16x8 h;
            h[0] = (f16)v0.x; h[1] = (f16)v0.y; h[2] = (f16)v0.z; h[3] = (f16)v0.w;
            h[4] = (f16)v1.x; h[5] = (f16)v1.y; h[6] = (f16)v1.z; h[7] = (f16)v1.w;
            wf[j][ks] = h;
        }
    }
    float bh[3][2];
#pragma unroll
    for (int g = 0; g < 3; g++)
#pragma unroll
        for (int hh = 0; hh < 2; hh++)
            bh[g][hh] = bhh[g * 128 + (wave + 4 * hh) * 16 + lr];

    int cur = 0;
    float pxA[2][4][3], pxB[2][4][3];

    auto loadpx = [&](int t, float (&px)[2][4][3]) {
#pragma unroll
        for (int hh = 0; hh < 2; hh++) {
            int d = (wave + 4 * hh) * 16 + lr;
#pragma unroll
            for (int r = 0; r < 4; r++) {
                const float* g = GX + (size_t)(t * 32 + b0 + lq * 4 + r) * 384 + d;
                px[hh][r][0] = g[0]; px[hh][r][1] = g[128]; px[hh][r][2] = g[256];
            }
        }
    };

    auto step = [&](int t, float (&pxU)[2][4][3], float (&pxN)[2][4][3]) {
        __syncthreads();
        float dtA = 1.f - dlds[t * 32 + b0 + lr];
        f16x8 af[4];
#pragma unroll
        for (int ks = 0; ks < 4; ks++) {
            const float* hr = &hlds[cur][lr][ks * 32 + lq * 8];
            float4 v0 = *(const float4*)hr, v1 = *(const float4*)(hr + 4);
            f16x8 h;
            h[0] = (f16)(v0.x * dtA); h[1] = (f16)(v0.y * dtA);
            h[2] = (f16)(v0.z * dtA); h[3] = (f16)(v0.w * dtA);
            h[4] = (f16)(v1.x * dtA); h[5] = (f16)(v1.y * dtA);
            h[6] = (f16)(v1.z * dtA); h[7] = (f16)(v1.w * dtA);
            af[ks] = h;
        }
        float dtb[4];
#pragma unroll
        for (int r = 0; r < 4; r++) dtb[r] = 1.f - dlds[t * 32 + b0 + lq * 4 + r];
        float hcm[2][4];
#pragma unroll
        for (int hh = 0; hh < 2; hh++) {
            int d = (wave + 4 * hh) * 16 + lr;
#pragma unroll
            for (int r = 0; r < 4; r++)
                hcm[hh][r] = hlds[cur][lq * 4 + r][d] * dtb[r];
        }
        // prefetch next step's gx — full MFMA+epilogue to hide the latency
        int tn = t + 1 < 64 ? t + 1 : 63;
        loadpx(tn, pxN);
        f32x4 acc[6] = {};
#pragma unroll
        for (int ks = 0; ks < 4; ks++) {
#pragma unroll
            for (int j = 0; j < 6; j++)
                acc[j] = __builtin_amdgcn_mfma_f32_16x16x32_f16(af[ks], wf[j][ks], acc[j], 0, 0, 0);
        }
        int nxt = cur ^ 1;
#pragma unroll
        for (int hh = 0; hh < 2; hh++) {
            int d = (wave + 4 * hh) * 16 + lr;
#pragma unroll
            for (int r = 0; r < 4; r++) {
                float sr = acc[0 + hh][r] + bh[0][hh];
                float sz = acc[2 + hh][r] + bh[1][hh];
                float sn = acc[4 + hh][r] + bh[2][hh];
                float rg = 1.f / (1.f + __expf(-(pxU[hh][r][0] + sr)));
                float zg = 1.f / (1.f + __expf(-(pxU[hh][r][1] + sz)));
                float a = pxU[hh][r][2] + rg * sn;
                float ng = 2.f / (1.f + __expf(-2.f * a)) - 1.f;   // tanh, saturates safely
                float hnew = (1.f - zg) * ng + zg * hcm[hh][r];
                hlds[nxt][lq * 4 + r][d] = hnew;
                hs[(size_t)(t * 32 + b0 + lq * 4 + r) * 128 + d] = hnew;
            }
        }
        cur = nxt;
    };

    loadpx(0, pxA);
    for (int t = 0; t < 64; t += 2) {
        step(t, pxA, pxB);
        step(t + 1, pxB, pxA);
    }
}

// ---------------- critic head ----------------
__global__ __launch_bounds__(256) void k_critic(const float* __restrict__ hs,
                                                const float* __restrict__ crw,
                                                const float* __restrict__ crb,
                                                float* __restrict__ out) {
    int wave = threadIdx.x >> 6, lane = threadIdx.x & 63;
    int row = blockIdx.x * 4 + wave;
    const float* hr = hs + (size_t)row * 128;
    float s = hr[lane] * crw[lane] + hr[64 + lane] * crw[64 + lane];
#pragma unroll
    for (int off = 32; off; off >>= 1) s += __shfl_down(s, off);
    if (lane == 0) out[row] = s + crb[0];
}

extern "C" void kernel_launch(void* const* d_in, const int* in_sizes, int n_in,
                              void* d_out, int out_size, void* d_ws, size_t ws_size,
                              hipStream_t stream) {
    const float* x     = (const float*)d_in[0];
    const float* done  = (const float*)d_in[1];
    const float* gru0  = (const float*)d_in[2];
    const float* c1w   = (const float*)d_in[3];
    const float* c1b   = (const float*)d_in[4];
    const float* c2w   = (const float*)d_in[5];
    const float* c2b   = (const float*)d_in[6];
    const float* c3w   = (const float*)d_in[7];
    const float* c3b   = (const float*)d_in[8];
    const float* fc1w  = (const float*)d_in[9];
    const float* fc2w  = (const float*)d_in[10];
    const float* spw   = (const float*)d_in[11];
    const float* qkvw  = (const float*)d_in[12];
    const float* projw = (const float*)d_in[13];
    const float* projb = (const float*)d_in[14];
    const float* fcw   = (const float*)d_in[15];
    const float* fcb   = (const float*)d_in[16];
    const float* wih   = (const float*)d_in[17];
    const float* whh   = (const float*)d_in[18];
    const float* bih   = (const float*)d_in[19];
    const float* bhh   = (const float*)d_in[20];
    const float* crw   = (const float*)d_in[21];
    const float* crb   = (const float*)d_in[22];
    float* out = (float*)d_out;

    f16* h1   = (f16*)d_ws;                 // 2048*784*32
    f16* h2   = h1 + 51380224ull;           // 2048*169*64
    f16* h3   = h2 + 22151168ull;           // 2048*36*64
    f16* f256 = h3 + 4718592ull;            // 2048*256
    f16* W1   = f256 + 524288ull;           // 8192
    f16* W2   = W1 + 8192;                  // 32768
    f16* W3   = W2 + 32768;                 // 36864
    f16* FCW  = W3 + 36864;                 // 589824
    f16* WIH  = FCW + 589824;               // 98304
    f16* QKVW = WIH + 98304;                // 12288
    f16* PROJW = QKVW + 12288;              // 4096
    float* zb  = (float*)(PROJW + 4096);    // 192 zero bias
    float* gxb = zb + 192;                  // 2048*384 fp32
    float* hsb = gxb + 786432;              // 64*32*128 fp32
    // h1 is dead after conv2 -> reuse for qkv / attout
    f16* qkv    = h1;                       // 73728*192
    f16* attout = h1 + 14155776ull;         // 73728*64

    k_prep<<<3056, 256, 0, stream>>>(c1w, c2w, c3w, fcw, wih, qkvw, projw,
                                     W1, W2, W3, FCW, WIH, QKVW, PROJW);
    hipMemsetAsync(zb, 0, 768, stream);

    k_conv<4, 8, 8, 4, 116, 28, 784, 32, true><<<25088, 256, 0, stream>>>(x, W1, c1b, h1);
    k_conv<32, 4, 4, 2, 28, 13, 169, 64, false><<<5408, 256, 0, stream>>>(h1, W2, c2b, h2);
    k_conv<64, 3, 3, 2, 13, 6, 36, 64, false><<<1152, 256, 0, stream>>>(h2, W3, c3b, h3);
    k_gate<<<512, 256, 0, stream>>>(h3, fc1w, fc2w, spw);
    // qkv = h3_gated @ QKVW^T  (M=73728, N=192, K=64)
    k_gemm16<false, false, false><<<dim3(3, 1152), 256, 0, stream>>>(h3, QKVW, zb, nullptr, qkv, 192, 64);
    k_attn<<<2048, 256, 0, stream>>>(qkv, attout);
    // h3 = attout @ PROJW^T + projb + h3  (residual fused)
    k_gemm16<false, false, true><<<dim3(1, 1152), 256, 0, stream>>>(attout, PROJW, projb, h3, h3, 64, 64);
    k_gemm16<true, false, false><<<dim3(4, 32), 256, 0, stream>>>(h3, FCW, fcb, nullptr, f256, 256, 2304);
    k_gemm16<false, true, false><<<dim3(6, 32), 256, 0, stream>>>(f256, WIH, bih, nullptr, gxb, 384, 256);
    k_gru<<<2, 256, 0, stream>>>(gxb, done, gru0, whh, bhh, hsb);
    k_critic<<<512, 256, 0, stream>>>(hsb, crw, crb, out);
}

// Round 4
// 1075.434 us; speedup vs baseline: 1.6374x; 1.0023x over previous
//
#include <hip/hip_runtime.h>
#include <math.h>

typedef _Float16 f16;
typedef f16 f16x8 __attribute__((ext_vector_type(8)));
typedef f16 f16x4 __attribute__((ext_vector_type(4)));
typedef f16 f16x2 __attribute__((ext_vector_type(2)));
typedef float f32x4 __attribute__((ext_vector_type(4)));

// ---------------- weight prep: fp32 -> fp16, conv weights to [n][k] with
// k-order matching the conv A-staging chunk layout ----------------
__global__ __launch_bounds__(256) void k_prep(const float* __restrict__ c1w,
                                              const float* __restrict__ c2w,
                                              const float* __restrict__ c3w,
                                              const float* __restrict__ fcw,
                                              const float* __restrict__ wih,
                                              const float* __restrict__ qkvw,
                                              const float* __restrict__ projw,
                                              f16* __restrict__ W1, f16* __restrict__ W2,
                                              f16* __restrict__ W3, f16* __restrict__ FCW,
                                              f16* __restrict__ WIH, f16* __restrict__ QKVW,
                                              f16* __restrict__ PROJW) {
    int i0 = blockIdx.x * 256 + threadIdx.x;
    if (i0 < 8192) {                       // conv1: k = kh*32 + c*8 + kw
        int n = i0 >> 8, k = i0 & 255;
        int kh = k >> 5, r = k & 31, c = r >> 3, kw = r & 7;
        W1[i0] = (f16)c1w[((n * 4 + c) * 8 + kh) * 8 + kw];
    } else if (i0 < 8192 + 32768) {        // conv2: k = kh*128 + kw*32 + c
        int i = i0 - 8192;
        int n = i >> 9, k = i & 511;
        int kh = k >> 7, r = k & 127, kw = r >> 5, c = r & 31;
        W2[i] = (f16)c2w[((n * 32 + c) * 4 + kh) * 4 + kw];
    } else if (i0 < 8192 + 32768 + 36864) {  // conv3: k = kh*192 + kw*64 + c
        int i = i0 - (8192 + 32768);
        int n = i / 576, k = i % 576;
        int kh = k / 192, r = k % 192, kw = r / 64, c = r & 63;
        W3[i] = (f16)c3w[((n * 64 + c) * 3 + kh) * 3 + kw];
    } else if (i0 < 8192 + 32768 + 36864 + 589824) {  // FC: k = p*64 + c (NHWC flat)
        int i = i0 - (8192 + 32768 + 36864);
        int o = i / 2304, k = i % 2304, p = k >> 6, c = k & 63;
        FCW[i] = (f16)fcw[o * 2304 + c * 36 + p];
    } else if (i0 < 765952) {
        int i = i0 - (8192 + 32768 + 36864 + 589824);
        WIH[i] = (f16)wih[i];
    } else if (i0 < 765952 + 12288) {      // qkv weight, q rows pre-scaled by 0.25
        int i = i0 - 765952;
        QKVW[i] = (f16)(qkvw[i] * ((i < 4096) ? 0.25f : 1.f));
    } else if (i0 < 765952 + 12288 + 4096) {
        int i = i0 - (765952 + 12288);
        PROJW[i] = (f16)projw[i];
    }
}

// ---------------- conv1: one block per sample, input read exactly once ----
// Rolling 12-row f16 window in LDS; 28 output-row phases; im2col LDS->LDS;
// MFMA 16x16x32; NHWC fp16 output restaged through LDS for f16x8 stores.
__global__ __launch_bounds__(256) void k_conv1(const float* __restrict__ x,
                                               const f16* __restrict__ W,   // [32][256]
                                               const float* __restrict__ bias,
                                               f16* __restrict__ dst) {
    __shared__ __attribute__((aligned(16))) f16 As[32 * 264];
    __shared__ __attribute__((aligned(16))) f16 Bs[32 * 264];
    __shared__ __attribute__((aligned(16))) f16 win[4][12][120];
    const int tid = threadIdx.x;
    const int wave = tid >> 6, lane = tid & 63;
    const int lr = lane & 15, lq = lane >> 4;
    const int n = blockIdx.x;
    const int mt = wave >> 1, nt = wave & 1;

    // stage weights once: Bs[ch][k], k = kh*32 + c*8 + kw
    for (int u = tid; u < 1024; u += 256)
        *(f16x8*)(Bs + (u >> 5) * 264 + (u & 31) * 8) = *(const f16x8*)(W + u * 8);
    // zero garbage A rows 28..31 (read by mt=1 MFMA, outputs discarded)
    for (int u = tid; u < 132; u += 256) {
        f16x8 z = {};
        *(f16x8*)(As + 28 * 264 + u * 8) = z;
    }
    const float bb = bias[nt * 16 + lr];
    const f16* ap = As + (mt * 16 + lr) * 264 + lq * 8;
    const f16* bp = Bs + (nt * 16 + lr) * 264 + lq * 8;
    const float* xb = x + (size_t)n * 4 * 116 * 116;

    for (int oy = 0; oy < 28; oy++) {
        // stage new input rows (8 at oy==0, else 4); 29 float4-chunks per row (116 = 29*4)
        int r0 = (oy == 0) ? 0 : oy * 4 + 4;
        int nu = (oy == 0) ? 928 : 464;
        for (int u = tid; u < nu; u += 256) {
            int ch4 = u % 29, rc = u / 29;
            int c = rc & 3, r = rc >> 2;
            int iy = r0 + r;
            float4 v = *(const float4*)(xb + ((size_t)c * 116 + iy) * 116 + ch4 * 4);
            f16x4 h;
            h[0] = (f16)v.x; h[1] = (f16)v.y; h[2] = (f16)v.z; h[3] = (f16)v.w;
            *(f16x4*)(&win[c][iy % 12][ch4 * 4]) = h;
        }
        __syncthreads();
        // im2col: As[px][kh*32 + c*8 + kw] = win[c][(oy*4+kh)%12][px*4 + kw]
        for (int u = tid; u < 896; u += 256) {
            int px = u >> 5, rr = u & 31;
            int kh = rr >> 2, c = rr & 3;
            const f16* s = &win[c][(oy * 4 + kh) % 12][px * 4];
            f16x4 a0 = *(const f16x4*)s;
            f16x4 a1 = *(const f16x4*)(s + 4);
            f16x8 h8;
            h8[0] = a0[0]; h8[1] = a0[1]; h8[2] = a0[2]; h8[3] = a0[3];
            h8[4] = a1[0]; h8[5] = a1[1]; h8[6] = a1[2]; h8[7] = a1[3];
            *(f16x8*)(As + px * 264 + kh * 32 + c * 8) = h8;
        }
        __syncthreads();
        f32x4 acc = {};
#pragma unroll
        for (int ks = 0; ks < 8; ks++) {
            f16x8 af = *(const f16x8*)(ap + ks * 32);
            f16x8 bf = *(const f16x8*)(bp + ks * 32);
            acc = __builtin_amdgcn_mfma_f32_16x16x32_f16(af, bf, acc, 0, 0, 0);
        }
        __syncthreads();   // all MFMA reads of As done -> reuse As[0..1792B] as out-stage
#pragma unroll
        for (int r = 0; r < 4; r++) {
            int px = mt * 16 + lq * 4 + r;
            if (px < 28)
                As[px * 32 + nt * 16 + lr] = (f16)fmaxf(acc[r] + bb, 0.f);
        }
        __syncthreads();
        if (tid < 112) {
            int px = tid >> 2, seg = tid & 3;
            *(f16x8*)(dst + ((size_t)n * 784 + oy * 28 + px) * 32 + seg * 8) =
                *(const f16x8*)(As + px * 32 + seg * 8);
        }
    }
}

// ---------------- implicit-GEMM MFMA conv (NHWC fp16 in/out, ReLU) --------
// XCD-aware chunked swizzle: consecutive work-tiles (same sample) -> same XCD L2.
template <int CINP, int KH, int KW, int STRIDE, int IW, int OW, int PPI, int NCH>
__global__ __launch_bounds__(256) void k_conv(const f16* __restrict__ src,
                                              const f16* __restrict__ W,  // [NCH][KH*CK]
                                              const float* __restrict__ bias,
                                              f16* __restrict__ dst) {
    constexpr int CK = KW * CINP;
    constexpr int KS = CK / 32;
    constexpr int NT = NCH / 16;
    constexpr int LA = CK + 8;
    constexpr int AUN = (64 * CK) / 8;
    constexpr int WUN = (NCH * CK) / 8;
    constexpr int ANU = (AUN + 255) / 256;
    constexpr int WNU = (WUN + 255) / 256;
    __shared__ f16 As[64 * LA];
    __shared__ f16 Bs[NCH * LA];
    const int tid = threadIdx.x;
    const int wave = tid >> 6, lane = tid & 63;
    int bid = blockIdx.x;
    int nwg = gridDim.x;
    int swz = ((nwg & 7) == 0) ? ((bid & 7) * (nwg >> 3) + (bid >> 3)) : bid;
    const int m0 = swz * 64;

    int aGB[ANU], aLO[ANU];
#pragma unroll
    for (int j = 0; j < ANU; j++) {
        int u = tid + j * 256;
        if (u < AUN) {
            constexpr int SPP = CK / 8;
            int px = u / SPP, seg = u % SPP;
            int m = m0 + px, n = m / PPI, pp = m % PPI, oy = pp / OW, ox = pp % OW;
            aGB[j] = ((n * IW + oy * STRIDE) * IW + ox * STRIDE) * CINP + seg * 8;
            aLO[j] = px * LA + seg * 8;
        }
    }
    int wGB[WNU], wLO[WNU];
#pragma unroll
    for (int j = 0; j < WNU; j++) {
        int u = tid + j * 256;
        if (u < WUN) {
            constexpr int SPP = CK / 8;
            int n = u / SPP, seg = u % SPP;
            wGB[j] = n * (KH * CK) + seg * 8;
            wLO[j] = n * LA + seg * 8;
        }
    }

    f32x4 acc[NT] = {};
    const f16* ap = As + (wave * 16 + (lane & 15)) * LA + (lane >> 4) * 8;
    const f16* bp = Bs + (lane & 15) * LA + (lane >> 4) * 8;

    for (int kh = 0; kh < KH; kh++) {
        __syncthreads();
#pragma unroll
        for (int j = 0; j < ANU; j++) {
            int u = tid + j * 256;
            if (u < AUN)
                *(f16x8*)(As + aLO[j]) = *(const f16x8*)(src + aGB[j] + kh * (IW * CINP));
        }
#pragma unroll
        for (int j = 0; j < WNU; j++) {
            int u = tid + j * 256;
            if (u < WUN)
                *(f16x8*)(Bs + wLO[j]) = *(const f16x8*)(W + wGB[j] + kh * CK);
        }
        __syncthreads();
#pragma unroll
        for (int ks = 0; ks < KS; ks++) {
            f16x8 af = *(const f16x8*)(ap + ks * 32);
#pragma unroll
            for (int nt = 0; nt < NT; nt++) {
                f16x8 bf = *(const f16x8*)(bp + nt * 16 * LA + ks * 32);
                acc[nt] = __builtin_amdgcn_mfma_f32_16x16x32_f16(af, bf, acc[nt], 0, 0, 0);
            }
        }
    }
    __syncthreads();
    {
        int rrow = wave * 16 + ((lane >> 4) << 2);
        int col = lane & 15;
#pragma unroll
        for (int nt = 0; nt < NT; nt++) {
            float bb = bias[nt * 16 + col];
#pragma unroll
            for (int r = 0; r < 4; r++) {
                float v = acc[nt][r] + bb;
                As[(rrow + r) * NCH + nt * 16 + col] = (f16)fmaxf(v, 0.f);
            }
        }
    }
    __syncthreads();
    constexpr int OUN = 64 * NCH / 8;
    for (int u = tid; u < OUN; u += 256) {
        int px = u / (NCH / 8), seg = u % (NCH / 8);
        *(f16x8*)(dst + (size_t)(m0 + px) * NCH + seg * 8) = *(const f16x8*)(As + px * NCH + seg * 8);
    }
}

// ---------------- MFMA GEMM: C = act(A(MxK,f16) @ W(NxK,f16)^T + bias [+ R]) ----
template <bool RELU, bool OUTF32, bool RESID>
__global__ __launch_bounds__(256) void k_gemm16(const f16* __restrict__ A,
                                                const f16* __restrict__ W,
                                                const float* __restrict__ bias,
                                                const f16* __restrict__ R,
                                                void* __restrict__ Cv, int N, int K) {
    __shared__ f16 As[64 * 72];
    __shared__ f16 Bs[64 * 72];
    int tid = threadIdx.x, wave = tid >> 6, lane = tid & 63;
    int n0 = blockIdx.x * 64, m0 = blockIdx.y * 64;
    f32x4 acc[4] = {};
    const f16* ap = As + (wave * 16 + (lane & 15)) * 72 + (lane >> 4) * 8;
    const f16* bp = Bs + (lane & 15) * 72 + (lane >> 4) * 8;
    int arow = tid >> 3, aseg = tid & 7;
    for (int k0 = 0; k0 < K; k0 += 64) {
        __syncthreads();
        *(f16x8*)(As + arow * 72 + aseg * 8) = *(const f16x8*)(A + (size_t)(m0 + arow) * K + k0 + aseg * 8);
        *(f16x8*)(As + (arow + 32) * 72 + aseg * 8) = *(const f16x8*)(A + (size_t)(m0 + arow + 32) * K + k0 + aseg * 8);
        *(f16x8*)(Bs + arow * 72 + aseg * 8) = *(const f16x8*)(W + (size_t)(n0 + arow) * K + k0 + aseg * 8);
        *(f16x8*)(Bs + (arow + 32) * 72 + aseg * 8) = *(const f16x8*)(W + (size_t)(n0 + arow + 32) * K + k0 + aseg * 8);
        __syncthreads();
#pragma unroll
        for (int ks = 0; ks < 2; ks++) {
            f16x8 af = *(const f16x8*)(ap + ks * 32);
#pragma unroll
            for (int nt = 0; nt < 4; nt++) {
                f16x8 bf = *(const f16x8*)(bp + nt * 16 * 72 + ks * 32);
                acc[nt] = __builtin_amdgcn_mfma_f32_16x16x32_f16(af, bf, acc[nt], 0, 0, 0);
            }
        }
    }
    int mrow = m0 + wave * 16 + ((lane >> 4) << 2);
    int col = n0 + (lane & 15);
#pragma unroll
    for (int nt = 0; nt < 4; nt++) {
        float bb = bias[col + nt * 16];
#pragma unroll
        for (int r = 0; r < 4; r++) {
            float v = acc[nt][r] + bb;
            if (RESID) v += (float)R[(size_t)(mrow + r) * N + col + nt * 16];
            if (RELU) v = fmaxf(v, 0.f);
            if (OUTF32) ((float*)Cv)[(size_t)(mrow + r) * N + col + nt * 16] = v;
            else ((f16*)Cv)[(size_t)(mrow + r) * N + col + nt * 16] = (f16)v;
        }
    }
}

// ---------------- CBAM channel+spatial gates, in-place on NHWC fp16 h3 ----
__global__ __launch_bounds__(256) void k_gate(f16* __restrict__ h3,
                                              const float* __restrict__ fc1w,
                                              const float* __restrict__ fc2w,
                                              const float* __restrict__ spw) {
    __shared__ float tok[4][36][67];
    __shared__ float pm[4][64], px[4][64], hml[4][32], chv[4][64];
    __shared__ float spm[4][36], spx[4][36], gsp[4][36];
    int s = threadIdx.x >> 6, lane = threadIdx.x & 63;
    f16* hb = h3 + (size_t)(blockIdx.x * 4 + s) * 2304;
    for (int i = lane; i < 2304; i += 64) tok[s][i >> 6][i & 63] = (float)hb[i];
    __syncthreads();
    {
        float m = 0.f, mx = -1e30f;
        for (int p = 0; p < 36; p++) { float v = tok[s][p][lane]; m += v; mx = fmaxf(mx, v); }
        pm[s][lane] = m * (1.f / 36.f); px[s][lane] = mx;
    }
    __syncthreads();
    if (lane < 32) {
        int j = lane & 15;
        const float* srcv = (lane < 16) ? pm[s] : px[s];
        float acc = 0.f;
        for (int c = 0; c < 64; c++) acc += fc1w[j * 64 + c] * srcv[c];
        hml[s][lane] = fmaxf(acc, 0.f);
    }
    __syncthreads();
    {
        float acc = 0.f;
        for (int j = 0; j < 16; j++) acc += fc2w[lane * 16 + j] * (hml[s][j] + hml[s][16 + j]);
        chv[s][lane] = 1.f / (1.f + expf(-acc));
    }
    __syncthreads();
    if (lane < 36) {
        float m = 0.f, mx = -1e30f;
        for (int c = 0; c < 64; c++) {
            float v = tok[s][lane][c] * chv[s][c];
            tok[s][lane][c] = v; m += v; mx = fmaxf(mx, v);
        }
        spm[s][lane] = m * (1.f / 64.f); spx[s][lane] = mx;
    }
    __syncthreads();
    if (lane < 36) {
        int y = lane / 6, x = lane % 6;
        float acc = 0.f;
        for (int dy = 0; dy < 7; dy++) {
            int yy = y + dy - 3; if (yy < 0 || yy > 5) continue;
            for (int dx = 0; dx < 7; dx++) {
                int xx = x + dx - 3; if (xx < 0 || xx > 5) continue;
                int pp = yy * 6 + xx;
                acc += spw[dy * 7 + dx] * spm[s][pp] + spw[49 + dy * 7 + dx] * spx[s][pp];
            }
        }
        gsp[s][lane] = 1.f / (1.f + expf(-acc));
    }
    __syncthreads();
    for (int i = lane; i < 2304; i += 64) {
        int p = i >> 6;
        hb[i] = (f16)(tok[s][p][i & 63] * gsp[s][p]);
    }
}

// ---------------- per-sample attention core: scores -> softmax -> PV ------
__global__ __launch_bounds__(256) void k_attn(const f16* __restrict__ qkv,
                                              f16* __restrict__ attout) {
    __shared__ f16 t[36][200];
    __shared__ f16 att[144][40];
    int tid = threadIdx.x;
    const f16* src = qkv + (size_t)blockIdx.x * 36 * 192;
    for (int i = tid; i < 864; i += 256) {
        int p = i / 24, seg = i % 24;
        *(f16x8*)(&t[p][seg * 8]) = *(const f16x8*)(src + p * 192 + seg * 8);
    }
    __syncthreads();
    for (int i = tid; i < 5184; i += 256) {
        int h = i / 1296, r = i % 1296, p = r / 36, p2 = r % 36;
        f16x8 qa = *(const f16x8*)(&t[p][h * 16]);
        f16x8 qb = *(const f16x8*)(&t[p][h * 16 + 8]);
        f16x8 ka = *(const f16x8*)(&t[p2][64 + h * 16]);
        f16x8 kb = *(const f16x8*)(&t[p2][64 + h * 16 + 8]);
        float s = 0.f;
#pragma unroll
        for (int j = 0; j < 8; j++)
            s += (float)qa[j] * (float)ka[j] + (float)qb[j] * (float)kb[j];
        att[h * 36 + p][p2] = (f16)s;
    }
    __syncthreads();
    if (tid < 144) {
        float mx = -1e30f;
        for (int j = 0; j < 36; j++) mx = fmaxf(mx, (float)att[tid][j]);
        float sum = 0.f; float e[36];
        for (int j = 0; j < 36; j++) { float v = __expf((float)att[tid][j] - mx); e[j] = v; sum += v; }
        float inv = 1.f / sum;
        for (int j = 0; j < 36; j++) att[tid][j] = (f16)(e[j] * inv);
    }
    __syncthreads();
    for (int i = tid; i < 1152; i += 256) {
        int p = i >> 5, cp = i & 31, c0 = cp * 2, h = c0 >> 4;
        const f16* ar = &att[h * 36 + p][0];
        float s0 = 0.f, s1 = 0.f;
        for (int p2 = 0; p2 < 36; p2++) {
            float a = (float)ar[p2];
            f16x2 vv = *(const f16x2*)(&t[p2][128 + c0]);
            s0 += a * (float)vv[0]; s1 += a * (float)vv[1];
        }
        f16x2 o; o[0] = (f16)s0; o[1] = (f16)s1;
        *(f16x2*)(attout + (size_t)blockIdx.x * 2304 + p * 64 + c0) = o;
    }
}

// ---------------- masked GRU scan: 2 blocks x 16 batches x 8 waves --------
// wave w owns output dims d in [w*16, w*16+16) for all 3 gates; whh f16 in regs;
// hidden state double-buffered fp32 in LDS; gx software-pipelined 1 step ahead.
__global__ __launch_bounds__(512, 1) void k_gru(const float* __restrict__ GX,
                                                const float* __restrict__ done,
                                                const float* __restrict__ h0,
                                                const float* __restrict__ whh,
                                                const float* __restrict__ bhh,
                                                float* __restrict__ hs) {
    __shared__ float hlds[2][16][132];
    __shared__ float dlds[2048];
    const int tid = threadIdx.x;
    const int wave = tid >> 6, lane = tid & 63;
    const int lr = lane & 15, lq = lane >> 4;
    const int b0 = blockIdx.x * 16;
    const int d = wave * 16 + lr;

    for (int i = tid; i < 2048; i += 512) dlds[i] = done[i];
    for (int i = tid; i < 2048; i += 512) hlds[0][i >> 7][i & 127] = h0[(size_t)b0 * 128 + i];

    // B-frags: wf[g][ks] <- whh row (g*128 + d), k = ks*32 + lq*8
    f16x8 wf[3][4];
#pragma unroll
    for (int g = 0; g < 3; g++) {
#pragma unroll
        for (int ks = 0; ks < 4; ks++) {
            const float* s = whh + (size_t)(g * 128 + d) * 128 + ks * 32 + lq * 8;
            float4 v0 = *(const float4*)s, v1 = *(const float4*)(s + 4);
            f16x8 h;
            h[0] = (f16)v0.x; h[1] = (f16)v0.y; h[2] = (f16)v0.z; h[3] = (f16)v0.w;
            h[4] = (f16)v1.x; h[5] = (f16)v1.y; h[6] = (f16)v1.z; h[7] = (f16)v1.w;
            wf[g][ks] = h;
        }
    }
    float bh[3];
#pragma unroll
    for (int g = 0; g < 3; g++) bh[g] = bhh[g * 128 + d];

    int cur = 0;
    float pxA[4][3], pxB[4][3];

    auto loadpx = [&](int t, float (&px)[4][3]) {
#pragma unroll
        for (int r = 0; r < 4; r++) {
            const float* g = GX + (size_t)(t * 32 + b0 + lq * 4 + r) * 384 + d;
            px[r][0] = g[0]; px[r][1] = g[128]; px[r][2] = g[256];
        }
    };

    auto step = [&](int t, float (&pxU)[4][3], float (&pxN)[4][3]) {
        __syncthreads();
        float dtA = 1.f - dlds[t * 32 + b0 + lr];
        f16x8 af[4];
#pragma unroll
        for (int ks = 0; ks < 4; ks++) {
            const float* hr = &hlds[cur][lr][ks * 32 + lq * 8];
            float4 v0 = *(const float4*)hr, v1 = *(const float4*)(hr + 4);
            f16x8 h;
            h[0] = (f16)(v0.x * dtA); h[1] = (f16)(v0.y * dtA);
            h[2] = (f16)(v0.z * dtA); h[3] = (f16)(v0.w * dtA);
            h[4] = (f16)(v1.x * dtA); h[5] = (f16)(v1.y * dtA);
            h[6] = (f16)(v1.z * dtA); h[7] = (f16)(v1.w * dtA);
            af[ks] = h;
        }
        float hcm[4];
#pragma unroll
        for (int r = 0; r < 4; r++) {
            float dtb = 1.f - dlds[t * 32 + b0 + lq * 4 + r];
            hcm[r] = hlds[cur][lq * 4 + r][d] * dtb;
        }
        int tn = t + 1 < 64 ? t + 1 : 63;
        loadpx(tn, pxN);   // prefetch, hidden under MFMA+epilogue
        f32x4 acc[3] = {};
#pragma unroll
        for (int ks = 0; ks < 4; ks++) {
#pragma unroll
            for (int g = 0; g < 3; g++)
                acc[g] = __builtin_amdgcn_mfma_f32_16x16x32_f16(af[ks], wf[g][ks], acc[g], 0, 0, 0);
        }
        int nxt = cur ^ 1;
#pragma unroll
        for (int r = 0; r < 4; r++) {
            float sr = acc[0][r] + bh[0];
            float sz = acc[1][r] + bh[1];
            float sn = acc[2][r] + bh[2];
            float rg = 1.f / (1.f + __expf(-(pxU[r][0] + sr)));
            float zg = 1.f / (1.f + __expf(-(pxU[r][1] + sz)));
            float a = pxU[r][2] + rg * sn;
            float ng = 2.f / (1.f + __expf(-2.f * a)) - 1.f;   // tanh
            float hnew = (1.f - zg) * ng + zg * hcm[r];
            hlds[nxt][lq * 4 + r][d] = hnew;
            hs[(size_t)(t * 32 + b0 + lq * 4 + r) * 128 + d] = hnew;
        }
        cur = nxt;
    };

    loadpx(0, pxA);
    for (int t = 0; t < 64; t += 2) {
        step(t, pxA, pxB);
        step(t + 1, pxB, pxA);
    }
}

// ---------------- critic head ----------------
__global__ __launch_bounds__(256) void k_critic(const float* __restrict__ hs,
                                                const float* __restrict__ crw,
                                                const float* __restrict__ crb,
                                                float* __restrict__ out) {
    int wave = threadIdx.x >> 6, lane = threadIdx.x & 63;
    int row = blockIdx.x * 4 + wave;
    const float* hr = hs + (size_t)row * 128;
    float s = hr[lane] * crw[lane] + hr[64 + lane] * crw[64 + lane];
#pragma unroll
    for (int off = 32; off; off >>= 1) s += __shfl_down(s, off);
    if (lane == 0) out[row] = s + crb[0];
}

extern "C" void kernel_launch(void* const* d_in, const int* in_sizes, int n_in,
                              void* d_out, int out_size, void* d_ws, size_t ws_size,
                              hipStream_t stream) {
    const float* x     = (const float*)d_in[0];
    const float* done  = (const float*)d_in[1];
    const float* gru0  = (const float*)d_in[2];
    const float* c1w   = (const float*)d_in[3];
    const float* c1b   = (const float*)d_in[4];
    const float* c2w   = (const float*)d_in[5];
    const float* c2b   = (const float*)d_in[6];
    const float* c3w   = (const float*)d_in[7];
    const float* c3b   = (const float*)d_in[8];
    const float* fc1w  = (const float*)d_in[9];
    const float* fc2w  = (const float*)d_in[10];
    const float* spw   = (const float*)d_in[11];
    const float* qkvw  = (const float*)d_in[12];
    const float* projw = (const float*)d_in[13];
    const float* projb = (const float*)d_in[14];
    const float* fcw   = (const float*)d_in[15];
    const float* fcb   = (const float*)d_in[16];
    const float* wih   = (const float*)d_in[17];
    const float* whh   = (const float*)d_in[18];
    const float* bih   = (const float*)d_in[19];
    const float* bhh   = (const float*)d_in[20];
    const float* crw   = (const float*)d_in[21];
    const float* crb   = (const float*)d_in[22];
    float* out = (float*)d_out;

    f16* h1   = (f16*)d_ws;                 // 2048*784*32
    f16* h2   = h1 + 51380224ull;           // 2048*169*64
    f16* h3   = h2 + 22151168ull;           // 2048*36*64
    f16* f256 = h3 + 4718592ull;            // 2048*256
    f16* W1   = f256 + 524288ull;           // 8192
    f16* W2   = W1 + 8192;                  // 32768
    f16* W3   = W2 + 32768;                 // 36864
    f16* FCW  = W3 + 36864;                 // 589824
    f16* WIH  = FCW + 589824;               // 98304
    f16* QKVW = WIH + 98304;                // 12288
    f16* PROJW = QKVW + 12288;              // 4096
    float* zb  = (float*)(PROJW + 4096);    // 192 zero bias
    float* gxb = zb + 192;                  // 2048*384 fp32
    float* hsb = gxb + 786432;              // 64*32*128 fp32
    // h1 is dead after conv2 -> reuse for qkv / attout
    f16* qkv    = h1;                       // 73728*192
    f16* attout = h1 + 14155776ull;         // 73728*64

    k_prep<<<3056, 256, 0, stream>>>(c1w, c2w, c3w, fcw, wih, qkvw, projw,
                                     W1, W2, W3, FCW, WIH, QKVW, PROJW);
    hipMemsetAsync(zb, 0, 768, stream);

    k_conv1<<<2048, 256, 0, stream>>>(x, W1, c1b, h1);
    k_conv<32, 4, 4, 2, 28, 13, 169, 64><<<5408, 256, 0, stream>>>(h1, W2, c2b, h2);
    k_conv<64, 3, 3, 2, 13, 6, 36, 64><<<1152, 256, 0, stream>>>(h2, W3, c3b, h3);
    k_gate<<<512, 256, 0, stream>>>(h3, fc1w, fc2w, spw);
    // qkv = h3_gated @ QKVW^T  (M=73728, N=192, K=64)
    k_gemm16<false, false, false><<<dim3(3, 1152), 256, 0, stream>>>(h3, QKVW, zb, nullptr, qkv, 192, 64);
    k_attn<<<2048, 256, 0, stream>>>(qkv, attout);
    // h3 = attout @ PROJW^T + projb + h3  (residual fused)
    k_gemm16<false, false, true><<<dim3(1, 1152), 256, 0, stream>>>(attout, PROJW, projb, h3, h3, 64, 64);
    k_gemm16<true, false, false><<<dim3(4, 32), 256, 0, stream>>>(h3, FCW, fcb, nullptr, f256, 256, 2304);
    k_gemm16<false, true, false><<<dim3(6, 32), 256, 0, stream>>>(f256, WIH, bih, nullptr, gxb, 384, 256);
    k_gru<<<2, 512, 0, stream>>>(gxb, done, gru0, whh, bhh, hsb);
    k_critic<<<512, 256, 0, stream>>>(hsb, crw, crb, out);
}

// Round 5
// 1067.688 us; speedup vs baseline: 1.6493x; 1.0073x over previous
//
#include <hip/hip_runtime.h>
#include <math.h>

typedef _Float16 f16;
typedef f16 f16x8 __attribute__((ext_vector_type(8)));
typedef f16 f16x4 __attribute__((ext_vector_type(4)));
typedef f16 f16x2 __attribute__((ext_vector_type(2)));
typedef float f32x4 __attribute__((ext_vector_type(4)));

// ---------------- weight prep: fp32 -> fp16, conv weights to [n][k] with
// k-order matching the conv A-staging chunk layout ----------------
__global__ __launch_bounds__(256) void k_prep(const float* __restrict__ c1w,
                                              const float* __restrict__ c2w,
                                              const float* __restrict__ c3w,
                                              const float* __restrict__ fcw,
                                              const float* __restrict__ wih,
                                              const float* __restrict__ qkvw,
                                              const float* __restrict__ projw,
                                              f16* __restrict__ W1, f16* __restrict__ W2,
                                              f16* __restrict__ W3, f16* __restrict__ FCW,
                                              f16* __restrict__ WIH, f16* __restrict__ QKVW,
                                              f16* __restrict__ PROJW) {
    int i0 = blockIdx.x * 256 + threadIdx.x;
    if (i0 < 8192) {                       // conv1: k = kh*32 + c*8 + kw
        int n = i0 >> 8, k = i0 & 255;
        int kh = k >> 5, r = k & 31, c = r >> 3, kw = r & 7;
        W1[i0] = (f16)c1w[((n * 4 + c) * 8 + kh) * 8 + kw];
    } else if (i0 < 8192 + 32768) {        // conv2: k = kh*128 + kw*32 + c
        int i = i0 - 8192;
        int n = i >> 9, k = i & 511;
        int kh = k >> 7, r = k & 127, kw = r >> 5, c = r & 31;
        W2[i] = (f16)c2w[((n * 32 + c) * 4 + kh) * 4 + kw];
    } else if (i0 < 8192 + 32768 + 36864) {  // conv3: k = kh*192 + kw*64 + c
        int i = i0 - (8192 + 32768);
        int n = i / 576, k = i % 576;
        int kh = k / 192, r = k % 192, kw = r / 64, c = r & 63;
        W3[i] = (f16)c3w[((n * 64 + c) * 3 + kh) * 3 + kw];
    } else if (i0 < 8192 + 32768 + 36864 + 589824) {  // FC: k = p*64 + c (NHWC flat)
        int i = i0 - (8192 + 32768 + 36864);
        int o = i / 2304, k = i % 2304, p = k >> 6, c = k & 63;
        FCW[i] = (f16)fcw[o * 2304 + c * 36 + p];
    } else if (i0 < 765952) {
        int i = i0 - (8192 + 32768 + 36864 + 589824);
        WIH[i] = (f16)wih[i];
    } else if (i0 < 765952 + 12288) {      // qkv weight, q rows pre-scaled by 0.25
        int i = i0 - 765952;
        QKVW[i] = (f16)(qkvw[i] * ((i < 4096) ? 0.25f : 1.f));
    } else if (i0 < 765952 + 12288 + 4096) {
        int i = i0 - (765952 + 12288);
        PROJW[i] = (f16)projw[i];
    }
}

// ---------------- conv1: one block per sample, input read exactly once ----
__global__ __launch_bounds__(256) void k_conv1(const float* __restrict__ x,
                                               const f16* __restrict__ W,   // [32][256]
                                               const float* __restrict__ bias,
                                               f16* __restrict__ dst) {
    __shared__ __attribute__((aligned(16))) f16 As[32 * 264];
    __shared__ __attribute__((aligned(16))) f16 Bs[32 * 264];
    __shared__ __attribute__((aligned(16))) f16 win[4][12][120];
    const int tid = threadIdx.x;
    const int wave = tid >> 6, lane = tid & 63;
    const int lr = lane & 15, lq = lane >> 4;
    const int n = blockIdx.x;
    const int mt = wave >> 1, nt = wave & 1;

    for (int u = tid; u < 1024; u += 256)
        *(f16x8*)(Bs + (u >> 5) * 264 + (u & 31) * 8) = *(const f16x8*)(W + u * 8);
    for (int u = tid; u < 132; u += 256) {
        f16x8 z = {};
        *(f16x8*)(As + 28 * 264 + u * 8) = z;
    }
    const float bb = bias[nt * 16 + lr];
    const f16* ap = As + (mt * 16 + lr) * 264 + lq * 8;
    const f16* bp = Bs + (nt * 16 + lr) * 264 + lq * 8;
    const float* xb = x + (size_t)n * 4 * 116 * 116;

    for (int oy = 0; oy < 28; oy++) {
        int r0 = (oy == 0) ? 0 : oy * 4 + 4;
        int nu = (oy == 0) ? 928 : 464;
        for (int u = tid; u < nu; u += 256) {
            int ch4 = u % 29, rc = u / 29;
            int c = rc & 3, r = rc >> 2;
            int iy = r0 + r;
            float4 v = *(const float4*)(xb + ((size_t)c * 116 + iy) * 116 + ch4 * 4);
            f16x4 h;
            h[0] = (f16)v.x; h[1] = (f16)v.y; h[2] = (f16)v.z; h[3] = (f16)v.w;
            *(f16x4*)(&win[c][iy % 12][ch4 * 4]) = h;
        }
        __syncthreads();
        for (int u = tid; u < 896; u += 256) {
            int px = u >> 5, rr = u & 31;
            int kh = rr >> 2, c = rr & 3;
            const f16* s = &win[c][(oy * 4 + kh) % 12][px * 4];
            f16x4 a0 = *(const f16x4*)s;
            f16x4 a1 = *(const f16x4*)(s + 4);
            f16x8 h8;
            h8[0] = a0[0]; h8[1] = a0[1]; h8[2] = a0[2]; h8[3] = a0[3];
            h8[4] = a1[0]; h8[5] = a1[1]; h8[6] = a1[2]; h8[7] = a1[3];
            *(f16x8*)(As + px * 264 + kh * 32 + c * 8) = h8;
        }
        __syncthreads();
        f32x4 acc = {};
#pragma unroll
        for (int ks = 0; ks < 8; ks++) {
            f16x8 af = *(const f16x8*)(ap + ks * 32);
            f16x8 bf = *(const f16x8*)(bp + ks * 32);
            acc = __builtin_amdgcn_mfma_f32_16x16x32_f16(af, bf, acc, 0, 0, 0);
        }
        __syncthreads();
#pragma unroll
        for (int r = 0; r < 4; r++) {
            int px = mt * 16 + lq * 4 + r;
            if (px < 28)
                As[px * 32 + nt * 16 + lr] = (f16)fmaxf(acc[r] + bb, 0.f);
        }
        __syncthreads();
        if (tid < 112) {
            int px = tid >> 2, seg = tid & 3;
            *(f16x8*)(dst + ((size_t)n * 784 + oy * 28 + px) * 32 + seg * 8) =
                *(const f16x8*)(As + px * 32 + seg * 8);
        }
    }
}

// ---------------- implicit-GEMM MFMA conv (NHWC fp16 in/out, ReLU) --------
template <int CINP, int KH, int KW, int STRIDE, int IW, int OW, int PPI, int NCH>
__global__ __launch_bounds__(256) void k_conv(const f16* __restrict__ src,
                                              const f16* __restrict__ W,  // [NCH][KH*CK]
                                              const float* __restrict__ bias,
                                              f16* __restrict__ dst) {
    constexpr int CK = KW * CINP;
    constexpr int KS = CK / 32;
    constexpr int NT = NCH / 16;
    constexpr int LA = CK + 8;
    constexpr int AUN = (64 * CK) / 8;
    constexpr int WUN = (NCH * CK) / 8;
    constexpr int ANU = (AUN + 255) / 256;
    constexpr int WNU = (WUN + 255) / 256;
    __shared__ f16 As[64 * LA];
    __shared__ f16 Bs[NCH * LA];
    const int tid = threadIdx.x;
    const int wave = tid >> 6, lane = tid & 63;
    int bid = blockIdx.x;
    int nwg = gridDim.x;
    int swz = ((nwg & 7) == 0) ? ((bid & 7) * (nwg >> 3) + (bid >> 3)) : bid;
    const int m0 = swz * 64;

    int aGB[ANU], aLO[ANU];
#pragma unroll
    for (int j = 0; j < ANU; j++) {
        int u = tid + j * 256;
        if (u < AUN) {
            constexpr int SPP = CK / 8;
            int px = u / SPP, seg = u % SPP;
            int m = m0 + px, n = m / PPI, pp = m % PPI, oy = pp / OW, ox = pp % OW;
            aGB[j] = ((n * IW + oy * STRIDE) * IW + ox * STRIDE) * CINP + seg * 8;
            aLO[j] = px * LA + seg * 8;
        }
    }
    int wGB[WNU], wLO[WNU];
#pragma unroll
    for (int j = 0; j < WNU; j++) {
        int u = tid + j * 256;
        if (u < WUN) {
            constexpr int SPP = CK / 8;
            int n = u / SPP, seg = u % SPP;
            wGB[j] = n * (KH * CK) + seg * 8;
            wLO[j] = n * LA + seg * 8;
        }
    }

    f32x4 acc[NT] = {};
    const f16* ap = As + (wave * 16 + (lane & 15)) * LA + (lane >> 4) * 8;
    const f16* bp = Bs + (lane & 15) * LA + (lane >> 4) * 8;

    for (int kh = 0; kh < KH; kh++) {
        __syncthreads();
#pragma unroll
        for (int j = 0; j < ANU; j++) {
            int u = tid + j * 256;
            if (u < AUN)
                *(f16x8*)(As + aLO[j]) = *(const f16x8*)(src + aGB[j] + kh * (IW * CINP));
        }
#pragma unroll
        for (int j = 0; j < WNU; j++) {
            int u = tid + j * 256;
            if (u < WUN)
                *(f16x8*)(Bs + wLO[j]) = *(const f16x8*)(W + wGB[j] + kh * CK);
        }
        __syncthreads();
#pragma unroll
        for (int ks = 0; ks < KS; ks++) {
            f16x8 af = *(const f16x8*)(ap + ks * 32);
#pragma unroll
            for (int nt = 0; nt < NT; nt++) {
                f16x8 bf = *(const f16x8*)(bp + nt * 16 * LA + ks * 32);
                acc[nt] = __builtin_amdgcn_mfma_f32_16x16x32_f16(af, bf, acc[nt], 0, 0, 0);
            }
        }
    }
    __syncthreads();
    {
        int rrow = wave * 16 + ((lane >> 4) << 2);
        int col = lane & 15;
#pragma unroll
        for (int nt = 0; nt < NT; nt++) {
            float bb = bias[nt * 16 + col];
#pragma unroll
            for (int r = 0; r < 4; r++) {
                float v = acc[nt][r] + bb;
                As[(rrow + r) * NCH + nt * 16 + col] = (f16)fmaxf(v, 0.f);
            }
        }
    }
    __syncthreads();
    constexpr int OUN = 64 * NCH / 8;
    for (int u = tid; u < OUN; u += 256) {
        int px = u / (NCH / 8), seg = u % (NCH / 8);
        *(f16x8*)(dst + (size_t)(m0 + px) * NCH + seg * 8) = *(const f16x8*)(As + px * NCH + seg * 8);
    }
}

// ---------------- MFMA GEMM: C = act(A(MxK,f16) @ W(NxK,f16)^T + bias) ----
template <bool RELU, bool OUTF32>
__global__ __launch_bounds__(256) void k_gemm16(const f16* __restrict__ A,
                                                const f16* __restrict__ W,
                                                const float* __restrict__ bias,
                                                void* __restrict__ Cv, int N, int K) {
    __shared__ f16 As[64 * 72];
    __shared__ f16 Bs[64 * 72];
    int tid = threadIdx.x, wave = tid >> 6, lane = tid & 63;
    int n0 = blockIdx.x * 64, m0 = blockIdx.y * 64;
    f32x4 acc[4] = {};
    const f16* ap = As + (wave * 16 + (lane & 15)) * 72 + (lane >> 4) * 8;
    const f16* bp = Bs + (lane & 15) * 72 + (lane >> 4) * 8;
    int arow = tid >> 3, aseg = tid & 7;
    for (int k0 = 0; k0 < K; k0 += 64) {
        __syncthreads();
        *(f16x8*)(As + arow * 72 + aseg * 8) = *(const f16x8*)(A + (size_t)(m0 + arow) * K + k0 + aseg * 8);
        *(f16x8*)(As + (arow + 32) * 72 + aseg * 8) = *(const f16x8*)(A + (size_t)(m0 + arow + 32) * K + k0 + aseg * 8);
        *(f16x8*)(Bs + arow * 72 + aseg * 8) = *(const f16x8*)(W + (size_t)(n0 + arow) * K + k0 + aseg * 8);
        *(f16x8*)(Bs + (arow + 32) * 72 + aseg * 8) = *(const f16x8*)(W + (size_t)(n0 + arow + 32) * K + k0 + aseg * 8);
        __syncthreads();
#pragma unroll
        for (int ks = 0; ks < 2; ks++) {
            f16x8 af = *(const f16x8*)(ap + ks * 32);
#pragma unroll
            for (int nt = 0; nt < 4; nt++) {
                f16x8 bf = *(const f16x8*)(bp + nt * 16 * 72 + ks * 32);
                acc[nt] = __builtin_amdgcn_mfma_f32_16x16x32_f16(af, bf, acc[nt], 0, 0, 0);
            }
        }
    }
    int mrow = m0 + wave * 16 + ((lane >> 4) << 2);
    int col = n0 + (lane & 15);
#pragma unroll
    for (int nt = 0; nt < 4; nt++) {
        float bb = bias[col + nt * 16];
#pragma unroll
        for (int r = 0; r < 4; r++) {
            float v = acc[nt][r] + bb;
            if (RELU) v = fmaxf(v, 0.f);
            if (OUTF32) ((float*)Cv)[(size_t)(mrow + r) * N + col + nt * 16] = v;
            else ((f16*)Cv)[(size_t)(mrow + r) * N + col + nt * 16] = (f16)v;
        }
    }
}

// ---------------- fused tail: conv3 + CBAM gates + QKV + attn + proj ------
// One sample per block. h2 tile staged to LDS once; conv3/qkv/proj via MFMA
// (weights L2-hot, B-frags in registers); everything LDS-resident; only the
// final h3 (FC input) is written to global.
__global__ __launch_bounds__(256, 2) void k_fuse3(const f16* __restrict__ h2,
                                                  const f16* __restrict__ W3,    // [64][576]
                                                  const float* __restrict__ c3b,
                                                  const float* __restrict__ fc1w,
                                                  const float* __restrict__ fc2w,
                                                  const float* __restrict__ spw,
                                                  const f16* __restrict__ QKVW,  // [192][64]
                                                  const f16* __restrict__ PROJW, // [64][64]
                                                  const float* __restrict__ projb,
                                                  f16* __restrict__ h3) {
    __shared__ __attribute__((aligned(16))) f16 h2t[12168];   // [13][13][72] padded
    __shared__ float tok[36][67];
    __shared__ __attribute__((aligned(16))) f16 tokh[48][72]; // gated tokens (qkv A)
    __shared__ __attribute__((aligned(16))) f16 t[48][200];   // q|k|v, then PV out in q
    __shared__ __attribute__((aligned(16))) f16 att[144][40];
    __shared__ float pm[64], pxm[64], hml[32], chv[64], spm[36], spx[36], gsp[36];
    const int tid = threadIdx.x, wave = tid >> 6, lane = tid & 63;
    const int lr = lane & 15, lq = lane >> 4;
    const int n = blockIdx.x;

    // stage h2 tile (13x13x64) -> padded LDS; coalesced f16x8
    const f16* hb2 = h2 + (size_t)n * 169 * 64;
    for (int u = tid; u < 1352; u += 256) {
        int iy = u / 104, rem = u % 104, ix = rem >> 3, seg = rem & 7;
        *(f16x8*)(h2t + iy * 936 + ix * 72 + seg * 8) = *(const f16x8*)(hb2 + (size_t)u * 8);
    }
    // zero pad rows 36..47 of t (cols 0..63) and tokh (all cols)
    if (tid < 204) {
        f16x8 z = {};
        if (tid < 96) { int r = tid >> 3, s = tid & 7; *(f16x8*)(&t[36 + r][s * 8]) = z; }
        else { int v = tid - 96; int r = v / 9, s = v % 9; *(f16x8*)(&tokh[36 + r][s * 8]) = z; }
    }

    // conv3 B-frags (wave's 16 output channels) -> registers, read once
    f16x8 b3[18];
    const f16* w3r = W3 + (wave * 16 + lr) * 576 + lq * 8;
#pragma unroll
    for (int ks = 0; ks < 18; ks++) b3[ks] = *(const f16x8*)(w3r + ks * 32);
    // per-lane A row bases for the 3 m-tiles (clamp garbage rows)
    int ob[3];
#pragma unroll
    for (int mt = 0; mt < 3; mt++) {
        int px = mt * 16 + lr; if (px > 35) px = 35;
        ob[mt] = (px / 6) * 2 * 936 + (px % 6) * 2 * 72;
    }
    const float cb = c3b[wave * 16 + lr];
    __syncthreads();

    // conv3: out[px][ch] = relu(sum_k A[px][k]*W3[ch][k] + bias)
#pragma unroll
    for (int mt = 0; mt < 3; mt++) {
        f32x4 acc = {};
#pragma unroll
        for (int ks = 0; ks < 18; ks++) {
            constexpr int KHL[18] = {0,0,0,0,0,0, 1,1,1,1,1,1, 2,2,2,2,2,2};
            constexpr int KWL[18] = {0,0,1,1,2,2, 0,0,1,1,2,2, 0,0,1,1,2,2};
            constexpr int C0L[18] = {0,32,0,32,0,32, 0,32,0,32,0,32, 0,32,0,32,0,32};
            f16x8 af = *(const f16x8*)(h2t + ob[mt] + KHL[ks] * 936 + KWL[ks] * 72 + C0L[ks] + lq * 8);
            acc = __builtin_amdgcn_mfma_f32_16x16x32_f16(af, b3[ks], acc, 0, 0, 0);
        }
#pragma unroll
        for (int r = 0; r < 4; r++) {
            int px = mt * 16 + lq * 4 + r;
            if (px < 36) tok[px][wave * 16 + lr] = fmaxf(acc[r] + cb, 0.f);
        }
    }
    __syncthreads();
    // CBAM channel attention
    if (tid < 64) {
        float m = 0.f, mx = -1e30f;
        for (int p = 0; p < 36; p++) { float v = tok[p][tid]; m += v; mx = fmaxf(mx, v); }
        pm[tid] = m * (1.f / 36.f); pxm[tid] = mx;
    }
    __syncthreads();
    if (tid < 32) {
        int j = tid & 15;
        const float* srcv = (tid < 16) ? pm : pxm;
        float a = 0.f;
        for (int c = 0; c < 64; c++) a += fc1w[j * 64 + c] * srcv[c];
        hml[tid] = fmaxf(a, 0.f);
    }
    __syncthreads();
    if (tid < 64) {
        float a = 0.f;
        for (int j = 0; j < 16; j++) a += fc2w[tid * 16 + j] * (hml[j] + hml[16 + j]);
        chv[tid] = 1.f / (1.f + expf(-a));
    }
    __syncthreads();
    if (tid < 36) {   // channel gate + spatial stats
        float m = 0.f, mx = -1e30f;
        for (int c = 0; c < 64; c++) {
            float v = tok[tid][c] * chv[c];
            tok[tid][c] = v; m += v; mx = fmaxf(mx, v);
        }
        spm[tid] = m * (1.f / 64.f); spx[tid] = mx;
    }
    __syncthreads();
    if (tid < 36) {   // 7x7 spatial conv on 6x6 mean/max maps
        int y = tid / 6, x = tid % 6;
        float a = 0.f;
        for (int dy = 0; dy < 7; dy++) {
            int yy = y + dy - 3; if (yy < 0 || yy > 5) continue;
            for (int dx = 0; dx < 7; dx++) {
                int xx = x + dx - 3; if (xx < 0 || xx > 5) continue;
                int pp = yy * 6 + xx;
                a += spw[dy * 7 + dx] * spm[pp] + spw[49 + dy * 7 + dx] * spx[pp];
            }
        }
        gsp[tid] = 1.f / (1.f + expf(-a));
    }
    __syncthreads();
    for (int i = tid; i < 2304; i += 256) {   // spatial gate; tok=residual, tokh=qkv A
        int p = i >> 6, c = i & 63;
        float v = tok[p][c] * gsp[p];
        tok[p][c] = v;
        tokh[p][c] = (f16)v;
    }
    __syncthreads();
    // QKV: wave handles n-tiles {w, w+4, w+8} of 12 (N=192, K=64)
#pragma unroll
    for (int j = 0; j < 3; j++) {
        int nt = wave + j * 4;
        int g = nt * 16 + lr;
        f16x8 bf0 = *(const f16x8*)(QKVW + g * 64 + lq * 8);
        f16x8 bf1 = *(const f16x8*)(QKVW + g * 64 + 32 + lq * 8);
        int which = g >> 6, col = g & 63;
#pragma unroll
        for (int mt = 0; mt < 3; mt++) {
            f16x8 a0 = *(const f16x8*)(&tokh[mt * 16 + lr][lq * 8]);
            f16x8 a1 = *(const f16x8*)(&tokh[mt * 16 + lr][32 + lq * 8]);
            f32x4 acc = {};
            acc = __builtin_amdgcn_mfma_f32_16x16x32_f16(a0, bf0, acc, 0, 0, 0);
            acc = __builtin_amdgcn_mfma_f32_16x16x32_f16(a1, bf1, acc, 0, 0, 0);
#pragma unroll
            for (int r = 0; r < 4; r++) {
                int px = mt * 16 + lq * 4 + r;
                if (px < 36) t[px][which * 64 + col] = (f16)acc[r];
            }
        }
    }
    __syncthreads();
    // scores (q pre-scaled)
    for (int i = tid; i < 5184; i += 256) {
        int h = i / 1296, r = i % 1296, p = r / 36, p2 = r % 36;
        f16x8 qa = *(const f16x8*)(&t[p][h * 16]);
        f16x8 qb = *(const f16x8*)(&t[p][h * 16 + 8]);
        f16x8 ka = *(const f16x8*)(&t[p2][64 + h * 16]);
        f16x8 kb = *(const f16x8*)(&t[p2][64 + h * 16 + 8]);
        float s = 0.f;
#pragma unroll
        for (int jj = 0; jj < 8; jj++)
            s += (float)qa[jj] * (float)ka[jj] + (float)qb[jj] * (float)kb[jj];
        att[h * 36 + p][p2] = (f16)s;
    }
    __syncthreads();
    if (tid < 144) {
        float mx = -1e30f;
        for (int j = 0; j < 36; j++) mx = fmaxf(mx, (float)att[tid][j]);
        float sum = 0.f; float e[36];
        for (int j = 0; j < 36; j++) { float v = __expf((float)att[tid][j] - mx); e[j] = v; sum += v; }
        float inv = 1.f / sum;
        for (int j = 0; j < 36; j++) att[tid][j] = (f16)(e[j] * inv);
    }
    __syncthreads();
    // PV -> overwrite q region of t
    for (int i = tid; i < 1152; i += 256) {
        int p = i >> 5, cp = i & 31, c0 = cp * 2, h = c0 >> 4;
        const f16* ar = &att[h * 36 + p][0];
        float s0 = 0.f, s1 = 0.f;
        for (int p2 = 0; p2 < 36; p2++) {
            float a = (float)ar[p2];
            f16x2 vv = *(const f16x2*)(&t[p2][128 + c0]);
            s0 += a * (float)vv[0]; s1 += a * (float)vv[1];
        }
        f16x2 o; o[0] = (f16)s0; o[1] = (f16)s1;
        *(f16x2*)(&t[p][c0]) = o;
    }
    __syncthreads();
    // proj (N=64, K=64) + residual + global h3 write
    {
        int c = wave * 16 + lr;
        f16x8 bf0 = *(const f16x8*)(PROJW + c * 64 + lq * 8);
        f16x8 bf1 = *(const f16x8*)(PROJW + c * 64 + 32 + lq * 8);
        float pb = projb[c];
#pragma unroll
        for (int mt = 0; mt < 3; mt++) {
            f16x8 a0 = *(const f16x8*)(&t[mt * 16 + lr][lq * 8]);
            f16x8 a1 = *(const f16x8*)(&t[mt * 16 + lr][32 + lq * 8]);
            f32x4 acc = {};
            acc = __builtin_amdgcn_mfma_f32_16x16x32_f16(a0, bf0, acc, 0, 0, 0);
            acc = __builtin_amdgcn_mfma_f32_16x16x32_f16(a1, bf1, acc, 0, 0, 0);
#pragma unroll
            for (int r = 0; r < 4; r++) {
                int px = mt * 16 + lq * 4 + r;
                if (px < 36)
                    h3[(size_t)n * 2304 + px * 64 + c] = (f16)(tok[px][c] + acc[r] + pb);
            }
        }
    }
}

// ---------------- masked GRU scan: 2 blocks x 16 batches x 8 waves --------
__global__ __launch_bounds__(512, 1) void k_gru(const float* __restrict__ GX,
                                                const float* __restrict__ done,
                                                const float* __restrict__ h0,
                                                const float* __restrict__ whh,
                                                const float* __restrict__ bhh,
                                                float* __restrict__ hs) {
    __shared__ float hlds[2][16][132];
    __shared__ float dlds[2048];
    const int tid = threadIdx.x;
    const int wave = tid >> 6, lane = tid & 63;
    const int lr = lane & 15, lq = lane >> 4;
    const int b0 = blockIdx.x * 16;
    const int d = wave * 16 + lr;

    for (int i = tid; i < 2048; i += 512) dlds[i] = done[i];
    for (int i = tid; i < 2048; i += 512) hlds[0][i >> 7][i & 127] = h0[(size_t)b0 * 128 + i];

    f16x8 wf[3][4];
#pragma unroll
    for (int g = 0; g < 3; g++) {
#pragma unroll
        for (int ks = 0; ks < 4; ks++) {
            const float* s = whh + (size_t)(g * 128 + d) * 128 + ks * 32 + lq * 8;
            float4 v0 = *(const float4*)s, v1 = *(const float4*)(s + 4);
            f16x8 h;
            h[0] = (f16)v0.x; h[1] = (f16)v0.y; h[2] = (f16)v0.z; h[3] = (f16)v0.w;
            h[4] = (f16)v1.x; h[5] = (f16)v1.y; h[6] = (f16)v1.z; h[7] = (f16)v1.w;
            wf[g][ks] = h;
        }
    }
    float bh[3];
#pragma unroll
    for (int g = 0; g < 3; g++) bh[g] = bhh[g * 128 + d];

    int cur = 0;
    float pxA[4][3], pxB[4][3];

    auto loadpx = [&](int t, float (&px)[4][3]) {
#pragma unroll
        for (int r = 0; r < 4; r++) {
            const float* g = GX + (size_t)(t * 32 + b0 + lq * 4 + r) * 384 + d;
            px[r][0] = g[0]; px[r][1] = g[128]; px[r][2] = g[256];
        }
    };

    auto step = [&](int t, float (&pxU)[4][3], float (&pxN)[4][3]) {
        __syncthreads();
        float dtA = 1.f - dlds[t * 32 + b0 + lr];
        f16x8 af[4];
#pragma unroll
        for (int ks = 0; ks < 4; ks++) {
            const float* hr = &hlds[cur][lr][ks * 32 + lq * 8];
            float4 v0 = *(const float4*)hr, v1 = *(const float4*)(hr + 4);
            f16x8 h;
            h[0] = (f16)(v0.x * dtA); h[1] = (f16)(v0.y * dtA);
            h[2] = (f16)(v0.z * dtA); h[3] = (f16)(v0.w * dtA);
            h[4] = (f16)(v1.x * dtA); h[5] = (f16)(v1.y * dtA);
            h[6] = (f16)(v1.z * dtA); h[7] = (f16)(v1.w * dtA);
            af[ks] = h;
        }
        float hcm[4];
#pragma unroll
        for (int r = 0; r < 4; r++) {
            float dtb = 1.f - dlds[t * 32 + b0 + lq * 4 + r];
            hcm[r] = hlds[cur][lq * 4 + r][d] * dtb;
        }
        int tn = t + 1 < 64 ? t + 1 : 63;
        loadpx(tn, pxN);
        f32x4 acc[3] = {};
#pragma unroll
        for (int ks = 0; ks < 4; ks++) {
#pragma unroll
            for (int g = 0; g < 3; g++)
                acc[g] = __builtin_amdgcn_mfma_f32_16x16x32_f16(af[ks], wf[g][ks], acc[g], 0, 0, 0);
        }
        int nxt = cur ^ 1;
#pragma unroll
        for (int r = 0; r < 4; r++) {
            float sr = acc[0][r] + bh[0];
            float sz = acc[1][r] + bh[1];
            float sn = acc[2][r] + bh[2];
            float rg = 1.f / (1.f + __expf(-(pxU[r][0] + sr)));
            float zg = 1.f / (1.f + __expf(-(pxU[r][1] + sz)));
            float a = pxU[r][2] + rg * sn;
            float ng = 2.f / (1.f + __expf(-2.f * a)) - 1.f;
            float hnew = (1.f - zg) * ng + zg * hcm[r];
            hlds[nxt][lq * 4 + r][d] = hnew;
            hs[(size_t)(t * 32 + b0 + lq * 4 + r) * 128 + d] = hnew;
        }
        cur = nxt;
    };

    loadpx(0, pxA);
    for (int t = 0; t < 64; t += 2) {
        step(t, pxA, pxB);
        step(t + 1, pxB, pxA);
    }
}

// ---------------- critic head ----------------
__global__ __launch_bounds__(256) void k_critic(const float* __restrict__ hs,
                                                const float* __restrict__ crw,
                                                const float* __restrict__ crb,
                                                float* __restrict__ out) {
    int wave = threadIdx.x >> 6, lane = threadIdx.x & 63;
    int row = blockIdx.x * 4 + wave;
    const float* hr = hs + (size_t)row * 128;
    float s = hr[lane] * crw[lane] + hr[64 + lane] * crw[64 + lane];
#pragma unroll
    for (int off = 32; off; off >>= 1) s += __shfl_down(s, off);
    if (lane == 0) out[row] = s + crb[0];
}

extern "C" void kernel_launch(void* const* d_in, const int* in_sizes, int n_in,
                              void* d_out, int out_size, void* d_ws, size_t ws_size,
                              hipStream_t stream) {
    const float* x     = (const float*)d_in[0];
    const float* done  = (const float*)d_in[1];
    const float* gru0  = (const float*)d_in[2];
    const float* c1w   = (const float*)d_in[3];
    const float* c1b   = (const float*)d_in[4];
    const float* c2w   = (const float*)d_in[5];
    const float* c2b   = (const float*)d_in[6];
    const float* c3w   = (const float*)d_in[7];
    const float* c3b   = (const float*)d_in[8];
    const float* fc1w  = (const float*)d_in[9];
    const float* fc2w  = (const float*)d_in[10];
    const float* spw   = (const float*)d_in[11];
    const float* qkvw  = (const float*)d_in[12];
    const float* projw = (const float*)d_in[13];
    const float* projb = (const float*)d_in[14];
    const float* fcw   = (const float*)d_in[15];
    const float* fcb   = (const float*)d_in[16];
    const float* wih   = (const float*)d_in[17];
    const float* whh   = (const float*)d_in[18];
    const float* bih   = (const float*)d_in[19];
    const float* bhh   = (const float*)d_in[20];
    const float* crw   = (const float*)d_in[21];
    const float* crb   = (const float*)d_in[22];
    float* out = (float*)d_out;

    f16* h1   = (f16*)d_ws;                 // 2048*784*32
    f16* h2   = h1 + 51380224ull;           // 2048*169*64
    f16* h3   = h2 + 22151168ull;           // 2048*36*64
    f16* f256 = h3 + 4718592ull;            // 2048*256
    f16* W1   = f256 + 524288ull;           // 8192
    f16* W2   = W1 + 8192;                  // 32768
    f16* W3   = W2 + 32768;                 // 36864
    f16* FCW  = W3 + 36864;                 // 589824
    f16* WIH  = FCW + 589824;               // 98304
    f16* QKVW = WIH + 98304;                // 12288
    f16* PROJW = QKVW + 12288;              // 4096
    float* gxb = (float*)(PROJW + 4096);    // 2048*384 fp32
    float* hsb = gxb + 786432;              // 64*32*128 fp32

    k_prep<<<3056, 256, 0, stream>>>(c1w, c2w, c3w, fcw, wih, qkvw, projw,
                                     W1, W2, W3, FCW, WIH, QKVW, PROJW);

    k_conv1<<<2048, 256, 0, stream>>>(x, W1, c1b, h1);
    k_conv<32, 4, 4, 2, 28, 13, 169, 64><<<5408, 256, 0, stream>>>(h1, W2, c2b, h2);
    k_fuse3<<<2048, 256, 0, stream>>>(h2, W3, c3b, fc1w, fc2w, spw, QKVW, PROJW, projb, h3);
    k_gemm16<true, false><<<dim3(4, 32), 256, 0, stream>>>(h3, FCW, fcb, f256, 256, 2304);
    k_gemm16<false, true><<<dim3(6, 32), 256, 0, stream>>>(f256, WIH, bih, gxb, 384, 256);
    k_gru<<<2, 512, 0, stream>>>(gxb, done, gru0, whh, bhh, hsb);
    k_critic<<<512, 256, 0, stream>>>(hsb, crw, crb, out);
}